// Round 1
// baseline (4278.381 us; speedup 1.0000x reference)
//
#include <hip/hip_runtime.h>
#include <cmath>

constexpr int Bc = 8;
constexpr int Nn = 10000;
constexpr int Ec = 320000;
constexpr int IN = 16;
constexpr int EH = 32;   // hidden
constexpr int EO = 32;   // edge out
constexpr int OD = 32;   // node out
constexpr int DF = 35;   // 2*IN + 2 + 1

// ws layout (floats): [0]=sum0 [1]=sum1 [2]=sumsq0 [3]=sumsq1 [4]=mean0 [5]=mean1 [6]=istd0 [7]=istd1

__global__ __launch_bounds__(256) void stats_kernel(const float* __restrict__ ea,
                                                    float* __restrict__ ws) {
    float s0 = 0.f, s1 = 0.f, q0 = 0.f, q1 = 0.f;
    for (int i = blockIdx.x * blockDim.x + threadIdx.x; i < Ec; i += gridDim.x * blockDim.x) {
        float2 v = reinterpret_cast<const float2*>(ea)[i];
        s0 += v.x; s1 += v.y; q0 += v.x * v.x; q1 += v.y * v.y;
    }
#pragma unroll
    for (int off = 32; off > 0; off >>= 1) {
        s0 += __shfl_down(s0, off);
        s1 += __shfl_down(s1, off);
        q0 += __shfl_down(q0, off);
        q1 += __shfl_down(q1, off);
    }
    if ((threadIdx.x & 63) == 0) {
        atomicAdd(&ws[0], s0);
        atomicAdd(&ws[1], s1);
        atomicAdd(&ws[2], q0);
        atomicAdd(&ws[3], q1);
    }
}

__global__ void finalize_stats(float* __restrict__ ws) {
    float s0 = ws[0], s1 = ws[1], q0 = ws[2], q1 = ws[3];
    float m0 = s0 / (float)Ec, m1 = s1 / (float)Ec;
    float v0 = (q0 - s0 * m0) / (float)(Ec - 1);
    float v1 = (q1 - s1 * m1) / (float)(Ec - 1);
    ws[4] = m0; ws[5] = m1;
    ws[6] = rsqrtf(v0); ws[7] = rsqrtf(v1);
}

__global__ __launch_bounds__(256) void edge_kernel(
    const float* __restrict__ x, const float* __restrict__ ea,
    const float* __restrict__ wmean, const float* __restrict__ wstd,
    const float* __restrict__ W1, const float* __restrict__ b1,
    const float* __restrict__ W2, const float* __restrict__ b2,
    const int* __restrict__ ei, const float* __restrict__ ws,
    float* __restrict__ agg)
{
    __shared__ float W1s[DF * EH];   // [f][o], transposed: W1s[f*32+o] = W1[o*35+f]
    __shared__ float W2s[EH * EO];   // [h][o], transposed
    __shared__ float b1s[EH];
    __shared__ float b2s[EO];
    const int tid = threadIdx.x;
    for (int i = tid; i < DF * EH; i += 256) {
        int f = i >> 5, o = i & 31;
        W1s[i] = W1[o * DF + f];
    }
    for (int i = tid; i < EH * EO; i += 256) {
        int h = i >> 5, o = i & 31;
        W2s[i] = W2[o * EH + h];
    }
    if (tid < EH) b1s[tid] = b1[tid];
    if (tid >= 64 && tid < 64 + EO) b2s[tid - 64] = b2[tid - 64];
    __syncthreads();

    const int e = blockIdx.x * 256 + tid;   // Ec == 1250*256 exactly, no tail
    const int b = blockIdx.y;
    const int src = ei[e];
    const int tgt = ei[Ec + e];

    const float4* xs = reinterpret_cast<const float4*>(x + ((size_t)b * Nn + src) * IN);
    const float4* xt = reinterpret_cast<const float4*>(x + ((size_t)b * Nn + tgt) * IN);
    float feat[DF];
    float4 v;
    v = xs[0]; feat[0]  = v.x; feat[1]  = v.y; feat[2]  = v.z; feat[3]  = v.w;
    v = xs[1]; feat[4]  = v.x; feat[5]  = v.y; feat[6]  = v.z; feat[7]  = v.w;
    v = xs[2]; feat[8]  = v.x; feat[9]  = v.y; feat[10] = v.z; feat[11] = v.w;
    v = xs[3]; feat[12] = v.x; feat[13] = v.y; feat[14] = v.z; feat[15] = v.w;
    v = xt[0]; feat[16] = v.x; feat[17] = v.y; feat[18] = v.z; feat[19] = v.w;
    v = xt[1]; feat[20] = v.x; feat[21] = v.y; feat[22] = v.z; feat[23] = v.w;
    v = xt[2]; feat[24] = v.x; feat[25] = v.y; feat[26] = v.z; feat[27] = v.w;
    v = xt[3]; feat[28] = v.x; feat[29] = v.y; feat[30] = v.z; feat[31] = v.w;

    float2 eav = reinterpret_cast<const float2*>(ea)[e];
    const float speed = feat[14] * wstd[0] + wmean[0];
    const float direc = feat[15] * wstd[1] + wmean[1];
    const float theta = fabsf(eav.y - direc);
    const float ewt = fmaxf(3.0f * speed * cosf(theta * 22.5f) / eav.x, 0.0f);
    feat[32] = (eav.x - ws[4]) * ws[6];
    feat[33] = (eav.y - ws[5]) * ws[7];
    feat[34] = ewt;

    float acc[EH];
#pragma unroll
    for (int o = 0; o < EH; ++o) acc[o] = b1s[o];
#pragma unroll
    for (int f = 0; f < DF; ++f) {
        const float fv = feat[f];
#pragma unroll
        for (int o = 0; o < EH; o += 4) {
            const float4 w = *reinterpret_cast<const float4*>(&W1s[f * EH + o]);
            acc[o + 0] += fv * w.x; acc[o + 1] += fv * w.y;
            acc[o + 2] += fv * w.z; acc[o + 3] += fv * w.w;
        }
    }
    float h[EH];
#pragma unroll
    for (int o = 0; o < EH; ++o) h[o] = 1.0f / (1.0f + __expf(-acc[o]));

    float acc2[EO];
#pragma unroll
    for (int o = 0; o < EO; ++o) acc2[o] = b2s[o];
#pragma unroll
    for (int hh = 0; hh < EH; ++hh) {
        const float fv = h[hh];
#pragma unroll
        for (int o = 0; o < EO; o += 4) {
            const float4 w = *reinterpret_cast<const float4*>(&W2s[hh * EO + o]);
            acc2[o + 0] += fv * w.x; acc2[o + 1] += fv * w.y;
            acc2[o + 2] += fv * w.z; acc2[o + 3] += fv * w.w;
        }
    }

    float* dst = agg + ((size_t)b * Nn + tgt) * EO;
#pragma unroll
    for (int o = 0; o < EO; ++o) {
        atomicAdd(&dst[o], 1.0f / (1.0f + __expf(-acc2[o])));
    }
}

__global__ __launch_bounds__(256) void node_kernel(
    const float* __restrict__ W3, const float* __restrict__ b3,
    float* __restrict__ out)
{
    __shared__ float W3s[EO * OD];  // [o][p], transposed: W3s[o*32+p] = W3[p*32+o]
    __shared__ float b3s[OD];
    const int tid = threadIdx.x;
    for (int i = tid; i < EO * OD; i += 256) {
        int o = i >> 5, p = i & 31;
        W3s[i] = W3[p * EO + o];
    }
    if (tid < OD) b3s[tid] = b3[tid];
    __syncthreads();

    const int idx = blockIdx.x * 256 + tid;
    if (idx >= Bc * Nn) return;
    float* row = out + (size_t)idx * OD;

    float a[EO];
#pragma unroll
    for (int i = 0; i < EO / 4; ++i) {
        float4 t = reinterpret_cast<float4*>(row)[i];
        a[4 * i] = t.x; a[4 * i + 1] = t.y; a[4 * i + 2] = t.z; a[4 * i + 3] = t.w;
    }
    float acc[OD];
#pragma unroll
    for (int p = 0; p < OD; ++p) acc[p] = b3s[p];
#pragma unroll
    for (int o = 0; o < EO; ++o) {
        const float av = a[o];
#pragma unroll
        for (int p = 0; p < OD; p += 4) {
            const float4 w = *reinterpret_cast<const float4*>(&W3s[o * OD + p]);
            acc[p + 0] += av * w.x; acc[p + 1] += av * w.y;
            acc[p + 2] += av * w.z; acc[p + 3] += av * w.w;
        }
    }
#pragma unroll
    for (int i = 0; i < OD / 4; ++i) {
        float4 t;
        t.x = 1.0f / (1.0f + __expf(-acc[4 * i + 0]));
        t.y = 1.0f / (1.0f + __expf(-acc[4 * i + 1]));
        t.z = 1.0f / (1.0f + __expf(-acc[4 * i + 2]));
        t.w = 1.0f / (1.0f + __expf(-acc[4 * i + 3]));
        reinterpret_cast<float4*>(row)[i] = t;
    }
}

extern "C" void kernel_launch(void* const* d_in, const int* in_sizes, int n_in,
                              void* d_out, int out_size, void* d_ws, size_t ws_size,
                              hipStream_t stream) {
    const float* x     = (const float*)d_in[0];
    const float* ea    = (const float*)d_in[1];
    const float* wmean = (const float*)d_in[2];
    const float* wstd  = (const float*)d_in[3];
    const float* W1    = (const float*)d_in[4];
    const float* b1    = (const float*)d_in[5];
    const float* W2    = (const float*)d_in[6];
    const float* b2    = (const float*)d_in[7];
    const float* W3    = (const float*)d_in[8];
    const float* b3    = (const float*)d_in[9];
    const int*   ei    = (const int*)d_in[10];
    float* out = (float*)d_out;
    float* ws  = (float*)d_ws;

    // d_out doubles as the agg accumulator; must be zeroed every launch.
    hipMemsetAsync(d_out, 0, (size_t)out_size * sizeof(float), stream);
    hipMemsetAsync(d_ws, 0, 8 * sizeof(float), stream);

    stats_kernel<<<256, 256, 0, stream>>>(ea, ws);
    finalize_stats<<<1, 1, 0, stream>>>(ws);
    edge_kernel<<<dim3(Ec / 256, Bc), 256, 0, stream>>>(x, ea, wmean, wstd,
                                                        W1, b1, W2, b2, ei, ws, out);
    node_kernel<<<(Bc * Nn + 255) / 256, 256, 0, stream>>>(W3, b3, out);
}

// Round 2
// 581.851 us; speedup vs baseline: 7.3531x; 7.3531x over previous
//
#include <hip/hip_runtime.h>
#include <cmath>

constexpr int Bc = 8;
constexpr int Nn = 10000;
constexpr int Ec = 320000;
constexpr int IN = 16;
constexpr int EH = 32;   // hidden
constexpr int EO = 32;   // edge out
constexpr int OD = 32;   // node out
constexpr int DF = 35;   // 2*IN + 2 + 1

// ws layout:
//   float ws[0..3]   : s0, s1, q0, q1        (zeroed each launch)
//   float ws[4..7]   : mean0, mean1, istd0, istd1
//   int   wi[8          .. 8+Nn)       : cnt      (zeroed each launch)
//   int   wi[8+Nn       .. 8+2*Nn)     : cursor   (filled by scan)
//   int   wi[8+2*Nn     .. 8+2*Nn+Ec)  : sorted   (filled by scatter)

__global__ __launch_bounds__(256) void stats_hist_kernel(const float* __restrict__ ea,
                                                         const int* __restrict__ ei,
                                                         float* __restrict__ ws) {
    int* cnt = (int*)ws + 8;
    float s0 = 0.f, s1 = 0.f, q0 = 0.f, q1 = 0.f;
    for (int i = blockIdx.x * blockDim.x + threadIdx.x; i < Ec; i += gridDim.x * blockDim.x) {
        float2 v = reinterpret_cast<const float2*>(ea)[i];
        s0 += v.x; s1 += v.y; q0 += v.x * v.x; q1 += v.y * v.y;
        atomicAdd(&cnt[ei[Ec + i]], 1);
    }
#pragma unroll
    for (int off = 32; off > 0; off >>= 1) {
        s0 += __shfl_down(s0, off);
        s1 += __shfl_down(s1, off);
        q0 += __shfl_down(q0, off);
        q1 += __shfl_down(q1, off);
    }
    if ((threadIdx.x & 63) == 0) {
        atomicAdd(&ws[0], s0);
        atomicAdd(&ws[1], s1);
        atomicAdd(&ws[2], q0);
        atomicAdd(&ws[3], q1);
    }
}

// One wave: finalize stats + exclusive-scan cnt -> cursor.
__global__ void scan_kernel(float* __restrict__ ws) {
    const int lane = threadIdx.x;
    if (lane == 0) {
        float s0 = ws[0], s1 = ws[1], q0 = ws[2], q1 = ws[3];
        float m0 = s0 / (float)Ec, m1 = s1 / (float)Ec;
        float v0 = (q0 - s0 * m0) / (float)(Ec - 1);
        float v1 = (q1 - s1 * m1) / (float)(Ec - 1);
        ws[4] = m0; ws[5] = m1;
        ws[6] = rsqrtf(v0); ws[7] = rsqrtf(v1);
    }
    int* cnt    = (int*)ws + 8;
    int* cursor = (int*)ws + 8 + Nn;
    int carry = 0;
    for (int base = 0; base < Nn; base += 64) {
        const int idx = base + lane;
        const int c = (idx < Nn) ? cnt[idx] : 0;
        int v = c;
#pragma unroll
        for (int off = 1; off < 64; off <<= 1) {
            int u = __shfl_up(v, off);
            if (lane >= off) v += u;
        }
        if (idx < Nn) cursor[idx] = carry + v - c;   // exclusive prefix
        carry += __shfl(v, 63);
    }
}

__global__ __launch_bounds__(256) void scatter_kernel(const int* __restrict__ ei,
                                                      float* __restrict__ ws) {
    int* cursor = (int*)ws + 8 + Nn;
    int* sorted = (int*)ws + 8 + 2 * Nn;
    const int e = blockIdx.x * 256 + threadIdx.x;   // Ec % 256 == 0
    const int tgt = ei[Ec + e];
    const int pos = atomicAdd(&cursor[tgt], 1);
    sorted[pos] = e;
}

__global__ __launch_bounds__(256) void edge_kernel(
    const float* __restrict__ x, const float* __restrict__ ea,
    const float* __restrict__ wmean, const float* __restrict__ wstd,
    const float* __restrict__ W1, const float* __restrict__ b1,
    const float* __restrict__ W2, const float* __restrict__ b2,
    const int* __restrict__ ei, const float* __restrict__ ws,
    float* __restrict__ agg)
{
    __shared__ float W1s[DF * EH];   // [f][o] transposed
    __shared__ float W2s[EH * EO];   // [h][o] transposed
    __shared__ float b1s[EH];
    __shared__ float b2s[EO];
    const int tid = threadIdx.x;
    for (int i = tid; i < DF * EH; i += 256) {
        int f = i >> 5, o = i & 31;
        W1s[i] = W1[o * DF + f];
    }
    for (int i = tid; i < EH * EO; i += 256) {
        int h = i >> 5, o = i & 31;
        W2s[i] = W2[o * EH + h];
    }
    if (tid < EH) b1s[tid] = b1[tid];
    if (tid >= 64 && tid < 64 + EO) b2s[tid - 64] = b2[tid - 64];
    __syncthreads();

    const int* sorted = (const int*)ws + 8 + 2 * Nn;
    const int gid = blockIdx.x * 256 + tid;
    const int b = blockIdx.y;
    const int e = sorted[gid];
    const int src = ei[e];
    const int tgt = ei[Ec + e];

    const float4* xs = reinterpret_cast<const float4*>(x + ((size_t)b * Nn + src) * IN);
    const float4* xt = reinterpret_cast<const float4*>(x + ((size_t)b * Nn + tgt) * IN);
    float feat[DF];
    float4 v4;
    v4 = xs[0]; feat[0]  = v4.x; feat[1]  = v4.y; feat[2]  = v4.z; feat[3]  = v4.w;
    v4 = xs[1]; feat[4]  = v4.x; feat[5]  = v4.y; feat[6]  = v4.z; feat[7]  = v4.w;
    v4 = xs[2]; feat[8]  = v4.x; feat[9]  = v4.y; feat[10] = v4.z; feat[11] = v4.w;
    v4 = xs[3]; feat[12] = v4.x; feat[13] = v4.y; feat[14] = v4.z; feat[15] = v4.w;
    v4 = xt[0]; feat[16] = v4.x; feat[17] = v4.y; feat[18] = v4.z; feat[19] = v4.w;
    v4 = xt[1]; feat[20] = v4.x; feat[21] = v4.y; feat[22] = v4.z; feat[23] = v4.w;
    v4 = xt[2]; feat[24] = v4.x; feat[25] = v4.y; feat[26] = v4.z; feat[27] = v4.w;
    v4 = xt[3]; feat[28] = v4.x; feat[29] = v4.y; feat[30] = v4.z; feat[31] = v4.w;

    const float2 eav = reinterpret_cast<const float2*>(ea)[e];
    const float speed = feat[14] * wstd[0] + wmean[0];
    const float direc = feat[15] * wstd[1] + wmean[1];
    const float theta = fabsf(eav.y - direc);
    const float ewt = fmaxf(3.0f * speed * cosf(theta * 22.5f) / eav.x, 0.0f);
    feat[32] = (eav.x - ws[4]) * ws[6];
    feat[33] = (eav.y - ws[5]) * ws[7];
    feat[34] = ewt;

    float acc[EH];
#pragma unroll
    for (int o = 0; o < EH; ++o) acc[o] = b1s[o];
#pragma unroll
    for (int f = 0; f < DF; ++f) {
        const float fv = feat[f];
#pragma unroll
        for (int o = 0; o < EH; o += 4) {
            const float4 w = *reinterpret_cast<const float4*>(&W1s[f * EH + o]);
            acc[o + 0] += fv * w.x; acc[o + 1] += fv * w.y;
            acc[o + 2] += fv * w.z; acc[o + 3] += fv * w.w;
        }
    }
    float h[EH];
#pragma unroll
    for (int o = 0; o < EH; ++o) h[o] = 1.0f / (1.0f + __expf(-acc[o]));

    float v[EO];
#pragma unroll
    for (int o = 0; o < EO; ++o) v[o] = b2s[o];
#pragma unroll
    for (int hh = 0; hh < EH; ++hh) {
        const float fv = h[hh];
#pragma unroll
        for (int o = 0; o < EO; o += 4) {
            const float4 w = *reinterpret_cast<const float4*>(&W2s[hh * EO + o]);
            v[o + 0] += fv * w.x; v[o + 1] += fv * w.y;
            v[o + 2] += fv * w.z; v[o + 3] += fv * w.w;
        }
    }
#pragma unroll
    for (int o = 0; o < EO; ++o) v[o] = 1.0f / (1.0f + __expf(-v[o]));

    // ---- wave-level segmented suffix-sum over runs of equal tgt ----
    const int lane = tid & 63;
    const int tprev = __shfl_up(tgt, 1);
    const bool head = (lane == 0) || (tprev != tgt);
#pragma unroll
    for (int off = 1; off < 64; off <<= 1) {
        const int tnext = __shfl_down(tgt, off);
        const bool ok = (lane + off < 64) && (tnext == tgt);
#pragma unroll
        for (int c = 0; c < EO; ++c) {
            const float u = __shfl_down(v[c], off);
            v[c] += ok ? u : 0.0f;
        }
    }
    if (head) {
        float* dst = agg + ((size_t)b * Nn + tgt) * EO;
#pragma unroll
        for (int c = 0; c < EO; ++c) atomicAdd(&dst[c], v[c]);
    }
}

__global__ __launch_bounds__(256) void node_kernel(
    const float* __restrict__ W3, const float* __restrict__ b3,
    float* __restrict__ out)
{
    __shared__ float W3s[EO * OD];
    __shared__ float b3s[OD];
    const int tid = threadIdx.x;
    for (int i = tid; i < EO * OD; i += 256) {
        int o = i >> 5, p = i & 31;
        W3s[i] = W3[p * EO + o];
    }
    if (tid < OD) b3s[tid] = b3[tid];
    __syncthreads();

    const int idx = blockIdx.x * 256 + tid;
    if (idx >= Bc * Nn) return;
    float* row = out + (size_t)idx * OD;

    float a[EO];
#pragma unroll
    for (int i = 0; i < EO / 4; ++i) {
        float4 t = reinterpret_cast<float4*>(row)[i];
        a[4 * i] = t.x; a[4 * i + 1] = t.y; a[4 * i + 2] = t.z; a[4 * i + 3] = t.w;
    }
    float acc[OD];
#pragma unroll
    for (int p = 0; p < OD; ++p) acc[p] = b3s[p];
#pragma unroll
    for (int o = 0; o < EO; ++o) {
        const float av = a[o];
#pragma unroll
        for (int p = 0; p < OD; p += 4) {
            const float4 w = *reinterpret_cast<const float4*>(&W3s[o * OD + p]);
            acc[p + 0] += av * w.x; acc[p + 1] += av * w.y;
            acc[p + 2] += av * w.z; acc[p + 3] += av * w.w;
        }
    }
#pragma unroll
    for (int i = 0; i < OD / 4; ++i) {
        float4 t;
        t.x = 1.0f / (1.0f + __expf(-acc[4 * i + 0]));
        t.y = 1.0f / (1.0f + __expf(-acc[4 * i + 1]));
        t.z = 1.0f / (1.0f + __expf(-acc[4 * i + 2]));
        t.w = 1.0f / (1.0f + __expf(-acc[4 * i + 3]));
        reinterpret_cast<float4*>(row)[i] = t;
    }
}

extern "C" void kernel_launch(void* const* d_in, const int* in_sizes, int n_in,
                              void* d_out, int out_size, void* d_ws, size_t ws_size,
                              hipStream_t stream) {
    const float* x     = (const float*)d_in[0];
    const float* ea    = (const float*)d_in[1];
    const float* wmean = (const float*)d_in[2];
    const float* wstd  = (const float*)d_in[3];
    const float* W1    = (const float*)d_in[4];
    const float* b1    = (const float*)d_in[5];
    const float* W2    = (const float*)d_in[6];
    const float* b2    = (const float*)d_in[7];
    const float* W3    = (const float*)d_in[8];
    const float* b3    = (const float*)d_in[9];
    const int*   ei    = (const int*)d_in[10];
    float* out = (float*)d_out;
    float* ws  = (float*)d_ws;

    // Zero: agg accumulator (=d_out), stats sums + histogram.
    hipMemsetAsync(d_out, 0, (size_t)out_size * sizeof(float), stream);
    hipMemsetAsync(d_ws, 0, (8 + Nn) * sizeof(float), stream);

    stats_hist_kernel<<<256, 256, 0, stream>>>(ea, ei, ws);
    scan_kernel<<<1, 64, 0, stream>>>(ws);
    scatter_kernel<<<Ec / 256, 256, 0, stream>>>(ei, ws);
    edge_kernel<<<dim3(Ec / 256, Bc), 256, 0, stream>>>(x, ea, wmean, wstd,
                                                        W1, b1, W2, b2, ei, ws, out);
    node_kernel<<<(Bc * Nn + 255) / 256, 256, 0, stream>>>(W3, b3, out);
}

// Round 3
// 481.217 us; speedup vs baseline: 8.8907x; 1.2091x over previous
//
#include <hip/hip_runtime.h>
#include <cmath>

constexpr int Bc = 8;
constexpr int Nn = 10000;
constexpr int Ec = 320000;
constexpr int IN = 16;
constexpr int EH = 32;
constexpr int EO = 32;
constexpr int OD = 32;

// ws layout (float offsets):
//   [0..3]  s0,s1,q0,q1   (zeroed)      [4..7] mean0,mean1,istd0,istd1
constexpr size_t S_CNT  = 8;                     // Nn ints (zeroed)
constexpr size_t S_CUR  = S_CNT + Nn;            // Nn ints
constexpr size_t S_SORT = S_CUR + Nn;            // Ec ints
constexpr size_t S_PA   = 340016;                // Bc*Nn*32 floats (16B aligned)
constexpr size_t S_PB   = S_PA + (size_t)Bc * Nn * 32;   // 2900016
constexpr size_t S_PW   = S_PB + (size_t)Bc * Nn * 32;   // 5460016, 2*Bc*Nn floats
// total = 5620016 floats = 22.5 MB

__device__ __forceinline__ float sigmoid_f(float x) {
    return __builtin_amdgcn_rcpf(1.0f + __expf(-x));
}

__global__ __launch_bounds__(256) void stats_hist_kernel(const float* __restrict__ ea,
                                                         const int* __restrict__ ei,
                                                         float* __restrict__ ws) {
    int* cnt = (int*)ws + S_CNT;
    float s0 = 0.f, s1 = 0.f, q0 = 0.f, q1 = 0.f;
    for (int i = blockIdx.x * blockDim.x + threadIdx.x; i < Ec; i += gridDim.x * blockDim.x) {
        float2 v = reinterpret_cast<const float2*>(ea)[i];
        s0 += v.x; s1 += v.y; q0 += v.x * v.x; q1 += v.y * v.y;
        atomicAdd(&cnt[ei[Ec + i]], 1);
    }
#pragma unroll
    for (int off = 32; off > 0; off >>= 1) {
        s0 += __shfl_down(s0, off);
        s1 += __shfl_down(s1, off);
        q0 += __shfl_down(q0, off);
        q1 += __shfl_down(q1, off);
    }
    if ((threadIdx.x & 63) == 0) {
        atomicAdd(&ws[0], s0);
        atomicAdd(&ws[1], s1);
        atomicAdd(&ws[2], q0);
        atomicAdd(&ws[3], q1);
    }
}

// One block, 256 threads (4 waves): finalize stats + exclusive scan cnt -> cursor.
__global__ void scan_kernel(float* __restrict__ ws) {
    const int tid = threadIdx.x;
    const int lane = tid & 63;
    const int w = tid >> 6;
    if (tid == 0) {
        float s0 = ws[0], s1 = ws[1], q0 = ws[2], q1 = ws[3];
        float m0 = s0 / (float)Ec, m1 = s1 / (float)Ec;
        float v0 = (q0 - s0 * m0) / (float)(Ec - 1);
        float v1 = (q1 - s1 * m1) / (float)(Ec - 1);
        ws[4] = m0; ws[5] = m1;
        ws[6] = rsqrtf(v0); ws[7] = rsqrtf(v1);
    }
    int* cnt    = (int*)ws + S_CNT;
    int* cursor = (int*)ws + S_CUR;
    __shared__ int wtot[4];
    constexpr int CHUNK = 2560;               // 4*2560 >= Nn
    const int lo = w * CHUNK;
    const int hi = min(Nn, lo + CHUNK);
    // pass 1: wave totals
    int sum = 0;
    for (int i = lo + lane; i < hi; i += 64) sum += cnt[i];
#pragma unroll
    for (int off = 32; off > 0; off >>= 1) sum += __shfl_down(sum, off);
    if (lane == 0) wtot[w] = sum;
    __syncthreads();
    int carry = 0;
    for (int k = 0; k < w; ++k) carry += wtot[k];
    // pass 2: scan
    for (int base = lo; base < hi; base += 64) {
        const int idx = base + lane;
        const int c = (idx < hi) ? cnt[idx] : 0;
        int v = c;
#pragma unroll
        for (int off = 1; off < 64; off <<= 1) {
            int u = __shfl_up(v, off);
            if (lane >= off) v += u;
        }
        if (idx < hi) cursor[idx] = carry + v - c;
        carry += __shfl(v, 63);
    }
}

__global__ __launch_bounds__(256) void scatter_kernel(const int* __restrict__ ei,
                                                      float* __restrict__ ws) {
    int* cursor = (int*)ws + S_CUR;
    int* sorted = (int*)ws + S_SORT;
    const int e = blockIdx.x * 256 + threadIdx.x;
    const int tgt = ei[Ec + e];
    const int pos = atomicAdd(&cursor[tgt], 1);
    sorted[pos] = e;
}

// Per (b,n): PA = W1[:, :16].x, PB = W1[:, 16:32].x + b1, PW = (3*speed, direc)
__global__ __launch_bounds__(256) void precompute_kernel(
    const float* __restrict__ x, const float* __restrict__ wmean,
    const float* __restrict__ wstd, const float* __restrict__ W1,
    const float* __restrict__ b1, float* __restrict__ ws)
{
    const int idx = blockIdx.x * 256 + threadIdx.x;
    if (idx >= Bc * Nn) return;
    const float4* xr = reinterpret_cast<const float4*>(x + (size_t)idx * IN);
    float xv[16];
    float4 t;
    t = xr[0]; xv[0]  = t.x; xv[1]  = t.y; xv[2]  = t.z; xv[3]  = t.w;
    t = xr[1]; xv[4]  = t.x; xv[5]  = t.y; xv[6]  = t.z; xv[7]  = t.w;
    t = xr[2]; xv[8]  = t.x; xv[9]  = t.y; xv[10] = t.z; xv[11] = t.w;
    t = xr[3]; xv[12] = t.x; xv[13] = t.y; xv[14] = t.z; xv[15] = t.w;

    float* PA = ws + S_PA + (size_t)idx * 32;
    float* PB = ws + S_PB + (size_t)idx * 32;
#pragma unroll
    for (int o = 0; o < 32; ++o) {
        const float* wr = W1 + o * 35;
        float a = 0.f, bb = b1[o];
#pragma unroll
        for (int f = 0; f < 16; ++f) {
            a  += xv[f] * wr[f];
            bb += xv[f] * wr[16 + f];
        }
        PA[o] = a;
        PB[o] = bb;
    }
    float2* PW = reinterpret_cast<float2*>(ws + S_PW);
    PW[idx] = make_float2(3.0f * (xv[14] * wstd[0] + wmean[0]),
                          xv[15] * wstd[1] + wmean[1]);
}

__global__ __launch_bounds__(256) void edge_kernel(
    const float* __restrict__ ea,
    const float* __restrict__ W1, const float* __restrict__ W2,
    const float* __restrict__ b2,
    const int* __restrict__ ei, const float* __restrict__ ws,
    float* __restrict__ agg)
{
    const int tid = threadIdx.x;
    const int bid = blockIdx.x;
    const int b = bid & 7;                       // XCD-resident batch
    const int gid = (bid >> 3) * 256 + tid;      // edge slot in sorted order

    const int* sorted = (const int*)ws + S_SORT;
    const int e = sorted[gid];
    const int src = ei[e];
    const int tgt = ei[Ec + e];
    const float2 eav = reinterpret_cast<const float2*>(ea)[e];

    const float2 pw = reinterpret_cast<const float2*>(ws + S_PW)[b * Nn + src];
    const float theta = fabsf(eav.y - pw.y);
    const float ewt = fmaxf(pw.x * __cosf(theta * 22.5f) * __builtin_amdgcn_rcpf(eav.x), 0.0f);
    const float f32v = (eav.x - ws[4]) * ws[6];
    const float f33v = (eav.y - ws[5]) * ws[7];

    const float4* par = reinterpret_cast<const float4*>(ws + S_PA + ((size_t)b * Nn + src) * 32);
    const float4* pbr = reinterpret_cast<const float4*>(ws + S_PB + ((size_t)b * Nn + tgt) * 32);

    float h[EH];
#pragma unroll
    for (int q = 0; q < 8; ++q) {
        const float4 a4 = par[q];
        const float4 b4 = pbr[q];
        const float av[4] = {a4.x, a4.y, a4.z, a4.w};
        const float bv[4] = {b4.x, b4.y, b4.z, b4.w};
#pragma unroll
        for (int j = 0; j < 4; ++j) {
            const int o = 4 * q + j;
            const float acc = av[j] + bv[j]
                            + f32v * W1[o * 35 + 32]
                            + f33v * W1[o * 35 + 33]
                            + ewt  * W1[o * 35 + 34];
            h[o] = sigmoid_f(acc);
        }
    }

    float v[EO];
#pragma unroll
    for (int o = 0; o < EO; ++o) {
        const float* wr = W2 + o * EH;           // uniform -> s_load
        float s = b2[o];
#pragma unroll
        for (int hh = 0; hh < EH; ++hh) s += h[hh] * wr[hh];
        v[o] = sigmoid_f(s);
    }

    // wave-level segmented suffix-sum over runs of equal tgt
    const int lane = tid & 63;
    const int tprev = __shfl_up(tgt, 1);
    const bool head = (lane == 0) || (tprev != tgt);
#pragma unroll
    for (int off = 1; off < 64; off <<= 1) {
        const int tnext = __shfl_down(tgt, off);
        const bool ok = (lane + off < 64) && (tnext == tgt);
#pragma unroll
        for (int c = 0; c < EO; ++c) {
            const float u = __shfl_down(v[c], off);
            v[c] += ok ? u : 0.0f;
        }
    }
    if (head) {
        float* dst = agg + ((size_t)b * Nn + tgt) * EO;
#pragma unroll
        for (int c = 0; c < EO; ++c) atomicAdd(&dst[c], v[c]);
    }
}

__global__ __launch_bounds__(256) void node_kernel(
    const float* __restrict__ W3, const float* __restrict__ b3,
    float* __restrict__ out)
{
    const int idx = blockIdx.x * 256 + threadIdx.x;
    if (idx >= Bc * Nn) return;
    float* row = out + (size_t)idx * OD;

    float a[EO];
#pragma unroll
    for (int i = 0; i < EO / 4; ++i) {
        float4 t = reinterpret_cast<float4*>(row)[i];
        a[4 * i] = t.x; a[4 * i + 1] = t.y; a[4 * i + 2] = t.z; a[4 * i + 3] = t.w;
    }
    float r[OD];
#pragma unroll
    for (int p = 0; p < OD; ++p) {
        const float* wr = W3 + p * EO;           // uniform -> s_load
        float s = b3[p];
#pragma unroll
        for (int o = 0; o < EO; ++o) s += a[o] * wr[o];
        r[p] = sigmoid_f(s);
    }
#pragma unroll
    for (int i = 0; i < OD / 4; ++i) {
        float4 t;
        t.x = r[4 * i + 0]; t.y = r[4 * i + 1];
        t.z = r[4 * i + 2]; t.w = r[4 * i + 3];
        reinterpret_cast<float4*>(row)[i] = t;
    }
}

extern "C" void kernel_launch(void* const* d_in, const int* in_sizes, int n_in,
                              void* d_out, int out_size, void* d_ws, size_t ws_size,
                              hipStream_t stream) {
    const float* x     = (const float*)d_in[0];
    const float* ea    = (const float*)d_in[1];
    const float* wmean = (const float*)d_in[2];
    const float* wstd  = (const float*)d_in[3];
    const float* W1    = (const float*)d_in[4];
    const float* b1    = (const float*)d_in[5];
    const float* W2    = (const float*)d_in[6];
    const float* b2    = (const float*)d_in[7];
    const float* W3    = (const float*)d_in[8];
    const float* b3    = (const float*)d_in[9];
    const int*   ei    = (const int*)d_in[10];
    float* out = (float*)d_out;
    float* ws  = (float*)d_ws;

    // d_out doubles as the agg accumulator; zero it + stats/histogram region.
    hipMemsetAsync(d_out, 0, (size_t)out_size * sizeof(float), stream);
    hipMemsetAsync(d_ws, 0, (S_CNT + Nn) * sizeof(float), stream);

    stats_hist_kernel<<<256, 256, 0, stream>>>(ea, ei, ws);
    scan_kernel<<<1, 256, 0, stream>>>(ws);
    scatter_kernel<<<Ec / 256, 256, 0, stream>>>(ei, ws);
    precompute_kernel<<<(Bc * Nn + 255) / 256, 256, 0, stream>>>(x, wmean, wstd, W1, b1, ws);
    edge_kernel<<<(Ec / 256) * Bc, 256, 0, stream>>>(ea, W1, W2, b2, ei, ws, out);
    node_kernel<<<(Bc * Nn + 255) / 256, 256, 0, stream>>>(W3, b3, out);
}

// Round 4
// 295.053 us; speedup vs baseline: 14.5004x; 1.6310x over previous
//
#include <hip/hip_runtime.h>
#include <cmath>

constexpr int Bc = 8;
constexpr int Nn = 10000;
constexpr int Ec = 320000;
constexpr int IN = 16;
constexpr int EH = 32;
constexpr int EO = 32;
constexpr int OD = 32;

// ws layout (float offsets):
//   [0..3]  s0,s1,q0,q1   (zeroed)      [4..7] mean0,mean1,istd0,istd1
constexpr size_t S_CNT  = 8;                     // Nn ints (zeroed)
constexpr size_t S_CUR  = S_CNT + Nn;            // Nn ints
constexpr size_t S_SORT = S_CUR + Nn;            // Ec ints
constexpr size_t S_PA   = 340016;                // Bc*Nn*32 floats (16B aligned)
constexpr size_t S_PB   = S_PA + (size_t)Bc * Nn * 32;
constexpr size_t S_PW   = S_PB + (size_t)Bc * Nn * 32;   // 2*Bc*Nn floats

typedef short bf16x8 __attribute__((ext_vector_type(8)));
typedef float f32x4 __attribute__((ext_vector_type(4)));

__device__ __forceinline__ float sigmoid_f(float x) {
    return __builtin_amdgcn_rcpf(1.0f + __expf(-x));
}
__device__ __forceinline__ unsigned bf16r(float f) {
    unsigned u = __builtin_bit_cast(unsigned, f);
    return (u + 0x7FFFu + ((u >> 16) & 1u)) >> 16;
}
__device__ __forceinline__ unsigned bf16pk(float lo, float hi) {
    return bf16r(lo) | (bf16r(hi) << 16);
}

__global__ __launch_bounds__(256) void stats_hist_kernel(const float* __restrict__ ea,
                                                         const int* __restrict__ ei,
                                                         float* __restrict__ ws) {
    int* cnt = (int*)ws + S_CNT;
    float s0 = 0.f, s1 = 0.f, q0 = 0.f, q1 = 0.f;
    for (int i = blockIdx.x * blockDim.x + threadIdx.x; i < Ec; i += gridDim.x * blockDim.x) {
        float2 v = reinterpret_cast<const float2*>(ea)[i];
        s0 += v.x; s1 += v.y; q0 += v.x * v.x; q1 += v.y * v.y;
        atomicAdd(&cnt[ei[Ec + i]], 1);
    }
#pragma unroll
    for (int off = 32; off > 0; off >>= 1) {
        s0 += __shfl_down(s0, off);
        s1 += __shfl_down(s1, off);
        q0 += __shfl_down(q0, off);
        q1 += __shfl_down(q1, off);
    }
    if ((threadIdx.x & 63) == 0) {
        atomicAdd(&ws[0], s0);
        atomicAdd(&ws[1], s1);
        atomicAdd(&ws[2], q0);
        atomicAdd(&ws[3], q1);
    }
}

// One block, 256 threads (4 waves): finalize stats + exclusive scan cnt -> cursor.
__global__ void scan_kernel(float* __restrict__ ws) {
    const int tid = threadIdx.x;
    const int lane = tid & 63;
    const int w = tid >> 6;
    if (tid == 0) {
        float s0 = ws[0], s1 = ws[1], q0 = ws[2], q1 = ws[3];
        float m0 = s0 / (float)Ec, m1 = s1 / (float)Ec;
        float v0 = (q0 - s0 * m0) / (float)(Ec - 1);
        float v1 = (q1 - s1 * m1) / (float)(Ec - 1);
        ws[4] = m0; ws[5] = m1;
        ws[6] = rsqrtf(v0); ws[7] = rsqrtf(v1);
    }
    int* cnt    = (int*)ws + S_CNT;
    int* cursor = (int*)ws + S_CUR;
    __shared__ int wtot[4];
    constexpr int CHUNK = 2560;
    const int lo = w * CHUNK;
    const int hi = min(Nn, lo + CHUNK);
    int sum = 0;
    for (int i = lo + lane; i < hi; i += 64) sum += cnt[i];
#pragma unroll
    for (int off = 32; off > 0; off >>= 1) sum += __shfl_down(sum, off);
    if (lane == 0) wtot[w] = sum;
    __syncthreads();
    int carry = 0;
    for (int k = 0; k < w; ++k) carry += wtot[k];
    for (int base = lo; base < hi; base += 64) {
        const int idx = base + lane;
        const int c = (idx < hi) ? cnt[idx] : 0;
        int v = c;
#pragma unroll
        for (int off = 1; off < 64; off <<= 1) {
            int u = __shfl_up(v, off);
            if (lane >= off) v += u;
        }
        if (idx < hi) cursor[idx] = carry + v - c;
        carry += __shfl(v, 63);
    }
}

__global__ __launch_bounds__(256) void scatter_kernel(const int* __restrict__ ei,
                                                      float* __restrict__ ws) {
    int* cursor = (int*)ws + S_CUR;
    int* sorted = (int*)ws + S_SORT;
    const int e = blockIdx.x * 256 + threadIdx.x;
    const int tgt = ei[Ec + e];
    const int pos = atomicAdd(&cursor[tgt], 1);
    sorted[pos] = e;
}

// Per (b,n): PA = W1[:, :16].x, PB = W1[:, 16:32].x + b1, PW = (3*speed, direc)
__global__ __launch_bounds__(256) void precompute_kernel(
    const float* __restrict__ x, const float* __restrict__ wmean,
    const float* __restrict__ wstd, const float* __restrict__ W1,
    const float* __restrict__ b1, float* __restrict__ ws)
{
    const int idx = blockIdx.x * 256 + threadIdx.x;
    if (idx >= Bc * Nn) return;
    const float4* xr = reinterpret_cast<const float4*>(x + (size_t)idx * IN);
    float xv[16];
    float4 t;
    t = xr[0]; xv[0]  = t.x; xv[1]  = t.y; xv[2]  = t.z; xv[3]  = t.w;
    t = xr[1]; xv[4]  = t.x; xv[5]  = t.y; xv[6]  = t.z; xv[7]  = t.w;
    t = xr[2]; xv[8]  = t.x; xv[9]  = t.y; xv[10] = t.z; xv[11] = t.w;
    t = xr[3]; xv[12] = t.x; xv[13] = t.y; xv[14] = t.z; xv[15] = t.w;

    float* PA = ws + S_PA + (size_t)idx * 32;
    float* PB = ws + S_PB + (size_t)idx * 32;
#pragma unroll
    for (int o = 0; o < 32; ++o) {
        const float* wr = W1 + o * 35;
        float a = 0.f, bb = b1[o];
#pragma unroll
        for (int f = 0; f < 16; ++f) {
            a  += xv[f] * wr[f];
            bb += xv[f] * wr[16 + f];
        }
        PA[o] = a;
        PB[o] = bb;
    }
    float2* PW = reinterpret_cast<float2*>(ws + S_PW);
    PW[idx] = make_float2(3.0f * (xv[14] * wstd[0] + wmean[0]),
                          xv[15] * wstd[1] + wmean[1]);
}

// LDS layout per wave (uint words): [0..1280) h-tile 64 rows x 20 (32 bf16 + pad)
//   [1280..2432) V-tile 32 rows x 36 (64 bf16 + pad)   [2432..2496) runid
//   [2496..2560) runtgt
__global__ __launch_bounds__(256, 4) void edge_kernel(
    const float* __restrict__ ea,
    const float* __restrict__ W1, const float* __restrict__ W2,
    const float* __restrict__ b2,
    const int* __restrict__ ei, const float* __restrict__ ws,
    float* __restrict__ agg)
{
    __shared__ unsigned lds[4 * 2560];
    const int tid  = threadIdx.x;
    const int lane = tid & 63;
    const int wid  = tid >> 6;
    unsigned* wl = lds + wid * 2560;

    const int bid = blockIdx.x;
    const int b   = bid & 7;                       // XCD-resident batch
    const int gid = (bid >> 3) * 256 + wid * 64 + lane;

    const int* sorted = (const int*)ws + S_SORT;
    const int e   = sorted[gid];
    const int src = ei[e];
    const int tgt = ei[Ec + e];
    const float2 eav = reinterpret_cast<const float2*>(ea)[e];

    // ---- phase 1: gather + layer-1 finish + sigmoid -> h (packed bf16) ----
    const float2 pw = reinterpret_cast<const float2*>(ws + S_PW)[b * Nn + src];
    const float theta = fabsf(eav.y - pw.y);
    const float ewt = fmaxf(pw.x * __cosf(theta * 22.5f) * __builtin_amdgcn_rcpf(eav.x), 0.0f);
    const float f32v = (eav.x - ws[4]) * ws[6];
    const float f33v = (eav.y - ws[5]) * ws[7];

    const float4* par = reinterpret_cast<const float4*>(ws + S_PA + ((size_t)b * Nn + src) * 32);
    const float4* pbr = reinterpret_cast<const float4*>(ws + S_PB + ((size_t)b * Nn + tgt) * 32);

    unsigned hw[16];
#pragma unroll
    for (int q = 0; q < 8; ++q) {
        const float4 a4 = par[q];
        const float4 b4 = pbr[q];
        const float av[4] = {a4.x, a4.y, a4.z, a4.w};
        const float bv[4] = {b4.x, b4.y, b4.z, b4.w};
        float hv[4];
#pragma unroll
        for (int j = 0; j < 4; ++j) {
            const int o = 4 * q + j;
            const float acc = av[j] + bv[j]
                            + f32v * W1[o * 35 + 32]
                            + f33v * W1[o * 35 + 33]
                            + ewt  * W1[o * 35 + 34];
            hv[j] = sigmoid_f(acc);
        }
        hw[2 * q]     = bf16pk(hv[0], hv[1]);
        hw[2 * q + 1] = bf16pk(hv[2], hv[3]);
    }
    {
        uint4* hrow = reinterpret_cast<uint4*>(wl + lane * 20);
#pragma unroll
        for (int q = 0; q < 4; ++q)
            hrow[q] = make_uint4(hw[4*q], hw[4*q+1], hw[4*q+2], hw[4*q+3]);
    }

    // ---- run ids (edges sorted by tgt) ----
    const int tprev = __shfl_up(tgt, 1);
    const bool head = (lane == 0) || (tprev != tgt);
    const unsigned long long mask = __ballot(head);
    const unsigned long long mle = (~0ULL) >> (63 - lane);
    const int run = __popcll(mask & mle) - 1;
    const int nruns = __popcll(mask);
    wl[2432 + lane] = (unsigned)run;
    if (head) wl[2496 + run] = (unsigned)tgt;

    const int c16 = lane & 15;
    const int hq  = lane >> 4;

    // ---- W2 B-frags: lane holds out=(c16+16t), k=8*hq+j ----
    bf16x8 bw[2];
#pragma unroll
    for (int t = 0; t < 2; ++t) {
        const float* wr = W2 + (c16 + 16 * t) * 32 + 8 * hq;
        const float4 w0 = *reinterpret_cast<const float4*>(wr);
        const float4 w1 = *reinterpret_cast<const float4*>(wr + 4);
        const uint4 pk = make_uint4(bf16pk(w0.x, w0.y), bf16pk(w0.z, w0.w),
                                    bf16pk(w1.x, w1.y), bf16pk(w1.z, w1.w));
        bw[t] = __builtin_bit_cast(bf16x8, pk);
    }

    // ---- MFMA1: C[edge][out] = H x W2^T ----
    f32x4 c[4][2];
#pragma unroll
    for (int m = 0; m < 4; ++m) {
        const uint4 av = *reinterpret_cast<const uint4*>(wl + (16 * m + c16) * 20 + 4 * hq);
        const bf16x8 afr = __builtin_bit_cast(bf16x8, av);
#pragma unroll
        for (int t = 0; t < 2; ++t) {
            f32x4 z = {0.f, 0.f, 0.f, 0.f};
            c[m][t] = __builtin_amdgcn_mfma_f32_16x16x32_bf16(afr, bw[t], z, 0, 0, 0);
        }
    }

    // ---- bias + sigmoid + pack V -> LDS [out][edge] bf16 ----
    const float b2v[2] = { b2[c16], b2[c16 + 16] };
#pragma unroll
    for (int m = 0; m < 4; ++m) {
#pragma unroll
        for (int t = 0; t < 2; ++t) {
            const float v0 = sigmoid_f(c[m][t][0] + b2v[t]);
            const float v1 = sigmoid_f(c[m][t][1] + b2v[t]);
            const float v2 = sigmoid_f(c[m][t][2] + b2v[t]);
            const float v3 = sigmoid_f(c[m][t][3] + b2v[t]);
            const uint2 pk = make_uint2(bf16pk(v0, v1), bf16pk(v2, v3));
            *reinterpret_cast<uint2*>(wl + 1280 + (c16 + 16 * t) * 36 + 8 * m + 2 * hq) = pk;
        }
    }

    // ---- read V B-frags + run ids ----
    bf16x8 vb[2][2];
    unsigned rid[2][8];
#pragma unroll
    for (int kk = 0; kk < 2; ++kk) {
#pragma unroll
        for (int t = 0; t < 2; ++t) {
            const uint4 vv = *reinterpret_cast<const uint4*>(wl + 1280 + (c16 + 16 * t) * 36 + 16 * kk + 4 * hq);
            vb[kk][t] = __builtin_bit_cast(bf16x8, vv);
        }
        const uint4 r0 = *reinterpret_cast<const uint4*>(wl + 2432 + 32 * kk + 8 * hq);
        const uint4 r1 = *reinterpret_cast<const uint4*>(wl + 2432 + 32 * kk + 8 * hq + 4);
        rid[kk][0] = r0.x; rid[kk][1] = r0.y; rid[kk][2] = r0.z; rid[kk][3] = r0.w;
        rid[kk][4] = r1.x; rid[kk][5] = r1.y; rid[kk][6] = r1.z; rid[kk][7] = r1.w;
    }

    // ---- MFMA2: agg_runs = I x V, then predicated atomics ----
    const int nm = (nruns + 15) >> 4;
    for (int mr = 0; mr < nm; ++mr) {
        const unsigned rowg = (unsigned)(16 * mr + c16);
        f32x4 d0 = {0.f, 0.f, 0.f, 0.f};
        f32x4 d1 = {0.f, 0.f, 0.f, 0.f};
#pragma unroll
        for (int kk = 0; kk < 2; ++kk) {
            unsigned iw[4];
#pragma unroll
            for (int w = 0; w < 4; ++w) {
                iw[w] = (rid[kk][2 * w]     == rowg ? 0x3f80u : 0u)
                      | (rid[kk][2 * w + 1] == rowg ? 0x3f800000u : 0u);
            }
            const bf16x8 ifr = __builtin_bit_cast(bf16x8, make_uint4(iw[0], iw[1], iw[2], iw[3]));
            d0 = __builtin_amdgcn_mfma_f32_16x16x32_bf16(ifr, vb[kk][0], d0, 0, 0, 0);
            d1 = __builtin_amdgcn_mfma_f32_16x16x32_bf16(ifr, vb[kk][1], d1, 0, 0, 0);
        }
#pragma unroll
        for (int r = 0; r < 4; ++r) {
            const int rn = 16 * mr + 4 * hq + r;
            const unsigned tr = wl[2496 + (rn & 63)];
            if (rn < nruns) {
                float* dst = agg + ((size_t)b * Nn + tr) * 32;
                atomicAdd(dst + c16,      d0[r]);
                atomicAdd(dst + c16 + 16, d1[r]);
            }
        }
    }
}

__global__ __launch_bounds__(256) void node_kernel(
    const float* __restrict__ W3, const float* __restrict__ b3,
    float* __restrict__ out)
{
    const int idx = blockIdx.x * 256 + threadIdx.x;
    if (idx >= Bc * Nn) return;
    float* row = out + (size_t)idx * OD;

    float a[EO];
#pragma unroll
    for (int i = 0; i < EO / 4; ++i) {
        float4 t = reinterpret_cast<float4*>(row)[i];
        a[4 * i] = t.x; a[4 * i + 1] = t.y; a[4 * i + 2] = t.z; a[4 * i + 3] = t.w;
    }
    float r[OD];
#pragma unroll
    for (int p = 0; p < OD; ++p) {
        const float* wr = W3 + p * EO;
        float s = b3[p];
#pragma unroll
        for (int o = 0; o < EO; ++o) s += a[o] * wr[o];
        r[p] = sigmoid_f(s);
    }
#pragma unroll
    for (int i = 0; i < OD / 4; ++i) {
        float4 t;
        t.x = r[4 * i + 0]; t.y = r[4 * i + 1];
        t.z = r[4 * i + 2]; t.w = r[4 * i + 3];
        reinterpret_cast<float4*>(row)[i] = t;
    }
}

extern "C" void kernel_launch(void* const* d_in, const int* in_sizes, int n_in,
                              void* d_out, int out_size, void* d_ws, size_t ws_size,
                              hipStream_t stream) {
    const float* x     = (const float*)d_in[0];
    const float* ea    = (const float*)d_in[1];
    const float* wmean = (const float*)d_in[2];
    const float* wstd  = (const float*)d_in[3];
    const float* W1    = (const float*)d_in[4];
    const float* b1    = (const float*)d_in[5];
    const float* W2    = (const float*)d_in[6];
    const float* b2    = (const float*)d_in[7];
    const float* W3    = (const float*)d_in[8];
    const float* b3    = (const float*)d_in[9];
    const int*   ei    = (const int*)d_in[10];
    float* out = (float*)d_out;
    float* ws  = (float*)d_ws;

    // d_out doubles as the agg accumulator; zero it + stats/histogram region.
    hipMemsetAsync(d_out, 0, (size_t)out_size * sizeof(float), stream);
    hipMemsetAsync(d_ws, 0, (S_CNT + Nn) * sizeof(float), stream);

    stats_hist_kernel<<<256, 256, 0, stream>>>(ea, ei, ws);
    scan_kernel<<<1, 256, 0, stream>>>(ws);
    scatter_kernel<<<Ec / 256, 256, 0, stream>>>(ei, ws);
    precompute_kernel<<<(Bc * Nn + 255) / 256, 256, 0, stream>>>(x, wmean, wstd, W1, b1, ws);
    edge_kernel<<<(Ec / 256) * Bc, 256, 0, stream>>>(ea, W1, W2, b2, ei, ws, out);
    node_kernel<<<(Bc * Nn + 255) / 256, 256, 0, stream>>>(W3, b3, out);
}

// Round 5
// 233.951 us; speedup vs baseline: 18.2875x; 1.2612x over previous
//
#include <hip/hip_runtime.h>
#include <hip/hip_fp16.h>
#include <cmath>

constexpr int Bc = 8;
constexpr int Nn = 10000;
constexpr int Ec = 320000;
constexpr int IN = 16;
constexpr int EH = 32;
constexpr int EO = 32;
constexpr int OD = 32;

// ws layout (u32 offsets):
//   [0..3] s0,s1,q0,q1 (zeroed, float)   [4..7] mean0,mean1,istd0,istd1 (float)
constexpr size_t U_CNT = 8;                             // Nn ints (zeroed)
constexpr size_t U_CUR = U_CNT + Nn;                    // Nn ints
constexpr size_t U_REC = 20016;                         // 4*Ec u32, 16B-aligned
constexpr size_t U_PA  = U_REC + 4 * (size_t)Ec;        // Bc*Nn*16 u32 (fp16x32 rows)
constexpr size_t U_PB  = U_PA + (size_t)Bc * Nn * 16;
constexpr size_t U_PW  = U_PB + (size_t)Bc * Nn * 16;   // 2*Bc*Nn u32 (float2)
// end = U_PW + 2*Bc*Nn = 4,020,016 u32 = 16.1 MB

typedef short bf16x8 __attribute__((ext_vector_type(8)));
typedef float f32x4 __attribute__((ext_vector_type(4)));

__device__ __forceinline__ float sigmoid_f(float x) {
    return __builtin_amdgcn_rcpf(1.0f + __expf(-x));
}
__device__ __forceinline__ unsigned bf16r(float f) {
    unsigned u = __builtin_bit_cast(unsigned, f);
    return (u + 0x7FFFu + ((u >> 16) & 1u)) >> 16;
}
__device__ __forceinline__ unsigned bf16pk(float lo, float hi) {
    return bf16r(lo) | (bf16r(hi) << 16);
}

__global__ __launch_bounds__(256) void stats_hist_kernel(const float* __restrict__ ea,
                                                         const int* __restrict__ ei,
                                                         float* __restrict__ ws) {
    int* cnt = (int*)ws + U_CNT;
    float s0 = 0.f, s1 = 0.f, q0 = 0.f, q1 = 0.f;
    for (int i = blockIdx.x * blockDim.x + threadIdx.x; i < Ec; i += gridDim.x * blockDim.x) {
        float2 v = reinterpret_cast<const float2*>(ea)[i];
        s0 += v.x; s1 += v.y; q0 += v.x * v.x; q1 += v.y * v.y;
        atomicAdd(&cnt[ei[Ec + i]], 1);
    }
#pragma unroll
    for (int off = 32; off > 0; off >>= 1) {
        s0 += __shfl_down(s0, off);
        s1 += __shfl_down(s1, off);
        q0 += __shfl_down(q0, off);
        q1 += __shfl_down(q1, off);
    }
    if ((threadIdx.x & 63) == 0) {
        atomicAdd(&ws[0], s0);
        atomicAdd(&ws[1], s1);
        atomicAdd(&ws[2], q0);
        atomicAdd(&ws[3], q1);
    }
}

// One block, 256 threads: finalize stats + exclusive scan cnt -> cursor.
__global__ void scan_kernel(float* __restrict__ ws) {
    const int tid = threadIdx.x;
    const int lane = tid & 63;
    const int w = tid >> 6;
    if (tid == 0) {
        float s0 = ws[0], s1 = ws[1], q0 = ws[2], q1 = ws[3];
        float m0 = s0 / (float)Ec, m1 = s1 / (float)Ec;
        float v0 = (q0 - s0 * m0) / (float)(Ec - 1);
        float v1 = (q1 - s1 * m1) / (float)(Ec - 1);
        ws[4] = m0; ws[5] = m1;
        ws[6] = rsqrtf(v0); ws[7] = rsqrtf(v1);
    }
    int* cnt    = (int*)ws + U_CNT;
    int* cursor = (int*)ws + U_CUR;
    __shared__ int wtot[4];
    constexpr int CHUNK = 2560;
    const int lo = w * CHUNK;
    const int hi = min(Nn, lo + CHUNK);
    int sum = 0;
    for (int i = lo + lane; i < hi; i += 64) sum += cnt[i];
#pragma unroll
    for (int off = 32; off > 0; off >>= 1) sum += __shfl_down(sum, off);
    if (lane == 0) wtot[w] = sum;
    __syncthreads();
    int carry = 0;
    for (int k = 0; k < w; ++k) carry += wtot[k];
    for (int base = lo; base < hi; base += 64) {
        const int idx = base + lane;
        const int c = (idx < hi) ? cnt[idx] : 0;
        int v = c;
#pragma unroll
        for (int off = 1; off < 64; off <<= 1) {
            int u = __shfl_up(v, off);
            if (lane >= off) v += u;
        }
        if (idx < hi) cursor[idx] = carry + v - c;
        carry += __shfl(v, 63);
    }
}

// Build sorted 16B edge records {src, tgt, ea.x, ea.y}.
__global__ __launch_bounds__(256) void record_kernel(const int* __restrict__ ei,
                                                     const float* __restrict__ ea,
                                                     float* __restrict__ ws) {
    int* cursor = (int*)ws + U_CUR;
    uint4* rec  = reinterpret_cast<uint4*>((unsigned*)ws + U_REC);
    const int e = blockIdx.x * 256 + threadIdx.x;
    const int src = ei[e];
    const int tgt = ei[Ec + e];
    const float2 v = reinterpret_cast<const float2*>(ea)[e];
    const int pos = atomicAdd(&cursor[tgt], 1);
    rec[pos] = make_uint4((unsigned)src, (unsigned)tgt,
                          __builtin_bit_cast(unsigned, v.x),
                          __builtin_bit_cast(unsigned, v.y));
}

// Per (b,n): PA = W1[:, :16].x (fp16x32), PB = W1[:, 16:32].x + b1 (fp16x32),
//            PW = (3*speed, direc) fp32x2
__global__ __launch_bounds__(256) void precompute_kernel(
    const float* __restrict__ x, const float* __restrict__ wmean,
    const float* __restrict__ wstd, const float* __restrict__ W1,
    const float* __restrict__ b1, float* __restrict__ ws)
{
    const int idx = blockIdx.x * 256 + threadIdx.x;
    if (idx >= Bc * Nn) return;
    const float4* xr = reinterpret_cast<const float4*>(x + (size_t)idx * IN);
    float xv[16];
    float4 t;
    t = xr[0]; xv[0]  = t.x; xv[1]  = t.y; xv[2]  = t.z; xv[3]  = t.w;
    t = xr[1]; xv[4]  = t.x; xv[5]  = t.y; xv[6]  = t.z; xv[7]  = t.w;
    t = xr[2]; xv[8]  = t.x; xv[9]  = t.y; xv[10] = t.z; xv[11] = t.w;
    t = xr[3]; xv[12] = t.x; xv[13] = t.y; xv[14] = t.z; xv[15] = t.w;

    __half2* PA = reinterpret_cast<__half2*>((unsigned*)ws + U_PA) + (size_t)idx * 16;
    __half2* PB = reinterpret_cast<__half2*>((unsigned*)ws + U_PB) + (size_t)idx * 16;
#pragma unroll
    for (int p = 0; p < 16; ++p) {
        float a[2], bb[2];
#pragma unroll
        for (int j = 0; j < 2; ++j) {
            const int o = 2 * p + j;
            const float* wr = W1 + o * 35;
            float av = 0.f, bv = b1[o];
#pragma unroll
            for (int f = 0; f < 16; ++f) {
                av += xv[f] * wr[f];
                bv += xv[f] * wr[16 + f];
            }
            a[j] = av; bb[j] = bv;
        }
        PA[p] = __half2{__float2half(a[0]), __float2half(a[1])};
        PB[p] = __half2{__float2half(bb[0]), __float2half(bb[1])};
    }
    float2* PW = reinterpret_cast<float2*>((unsigned*)ws + U_PW);
    PW[idx] = make_float2(3.0f * (xv[14] * wstd[0] + wmean[0]),
                          xv[15] * wstd[1] + wmean[1]);
}

// LDS layout per wave (u32 words): [0..1280) h-tile 64 rows x 20 (32 bf16 + pad)
//   [1280..2432) V-tile 32 rows x 36   [2432..2496) runid   [2496..2560) runtgt
__global__ __launch_bounds__(256, 4) void edge_kernel(
    const float* __restrict__ W1, const float* __restrict__ W2,
    const float* __restrict__ b2, const float* __restrict__ ws,
    float* __restrict__ agg)
{
    __shared__ unsigned lds[4 * 2560];
    const int tid  = threadIdx.x;
    const int lane = tid & 63;
    const int wid  = tid >> 6;
    unsigned* wl = lds + wid * 2560;

    const int bid = blockIdx.x;
    const int b   = bid & 7;                       // XCD-resident batch
    const int gid = (bid >> 3) * 256 + wid * 64 + lane;

    const unsigned* wsu = (const unsigned*)ws;
    const uint4 rec = reinterpret_cast<const uint4*>(wsu + U_REC)[gid];
    const int src = (int)rec.x;
    const int tgt = (int)rec.y;
    const float eax = __builtin_bit_cast(float, rec.z);
    const float eay = __builtin_bit_cast(float, rec.w);

    // ---- phase 1: gather + layer-1 finish + sigmoid -> h (packed bf16) ----
    const float2 pw = reinterpret_cast<const float2*>(wsu + U_PW)[b * Nn + src];
    const float theta = fabsf(eay - pw.y);
    const float ewt = fmaxf(pw.x * __cosf(theta * 22.5f) * __builtin_amdgcn_rcpf(eax), 0.0f);
    const float f32v = (eax - ws[4]) * ws[6];
    const float f33v = (eay - ws[5]) * ws[7];

    const uint4* pa4 = reinterpret_cast<const uint4*>(wsu + U_PA + ((size_t)b * Nn + src) * 16);
    const uint4* pb4 = reinterpret_cast<const uint4*>(wsu + U_PB + ((size_t)b * Nn + tgt) * 16);

    unsigned hw[16];
#pragma unroll
    for (int q = 0; q < 4; ++q) {
        const uint4 ua = pa4[q];
        const uint4 ub = pb4[q];
        const unsigned au[4] = {ua.x, ua.y, ua.z, ua.w};
        const unsigned bu[4] = {ub.x, ub.y, ub.z, ub.w};
#pragma unroll
        for (int j = 0; j < 4; ++j) {
            const int p = 4 * q + j;            // half2 index: outputs 2p, 2p+1
            const __half2 s = __hadd2(__builtin_bit_cast(__half2, au[j]),
                                      __builtin_bit_cast(__half2, bu[j]));
            const float2 f = __half22float2(s);
            const int o0 = 2 * p, o1 = 2 * p + 1;
            const float acc0 = f.x + f32v * W1[o0 * 35 + 32]
                                   + f33v * W1[o0 * 35 + 33]
                                   + ewt  * W1[o0 * 35 + 34];
            const float acc1 = f.y + f32v * W1[o1 * 35 + 32]
                                   + f33v * W1[o1 * 35 + 33]
                                   + ewt  * W1[o1 * 35 + 34];
            hw[p] = bf16pk(sigmoid_f(acc0), sigmoid_f(acc1));
        }
    }
    {
        uint4* hrow = reinterpret_cast<uint4*>(wl + lane * 20);
#pragma unroll
        for (int q = 0; q < 4; ++q)
            hrow[q] = make_uint4(hw[4*q], hw[4*q+1], hw[4*q+2], hw[4*q+3]);
    }

    // ---- run ids (edges sorted by tgt) ----
    const int tprev = __shfl_up(tgt, 1);
    const bool head = (lane == 0) || (tprev != tgt);
    const unsigned long long mask = __ballot(head);
    const unsigned long long mle = (~0ULL) >> (63 - lane);
    const int run = __popcll(mask & mle) - 1;
    const int nruns = __popcll(mask);
    wl[2432 + lane] = (unsigned)run;
    if (head) wl[2496 + run] = (unsigned)tgt;

    const int c16 = lane & 15;
    const int hq  = lane >> 4;

    // ---- W2 B-frags: lane holds out=(c16+16t), k=8*hq+j ----
    bf16x8 bw[2];
#pragma unroll
    for (int t = 0; t < 2; ++t) {
        const float* wr = W2 + (c16 + 16 * t) * 32 + 8 * hq;
        const float4 w0 = *reinterpret_cast<const float4*>(wr);
        const float4 w1 = *reinterpret_cast<const float4*>(wr + 4);
        const uint4 pk = make_uint4(bf16pk(w0.x, w0.y), bf16pk(w0.z, w0.w),
                                    bf16pk(w1.x, w1.y), bf16pk(w1.z, w1.w));
        bw[t] = __builtin_bit_cast(bf16x8, pk);
    }

    // ---- MFMA1: C[edge][out] = H x W2^T ----
    f32x4 c[4][2];
#pragma unroll
    for (int m = 0; m < 4; ++m) {
        const uint4 av = *reinterpret_cast<const uint4*>(wl + (16 * m + c16) * 20 + 4 * hq);
        const bf16x8 afr = __builtin_bit_cast(bf16x8, av);
#pragma unroll
        for (int t = 0; t < 2; ++t) {
            f32x4 z = {0.f, 0.f, 0.f, 0.f};
            c[m][t] = __builtin_amdgcn_mfma_f32_16x16x32_bf16(afr, bw[t], z, 0, 0, 0);
        }
    }

    // ---- bias + sigmoid + pack V -> LDS [out][edge] bf16 ----
    const float b2v[2] = { b2[c16], b2[c16 + 16] };
#pragma unroll
    for (int m = 0; m < 4; ++m) {
#pragma unroll
        for (int t = 0; t < 2; ++t) {
            const float v0 = sigmoid_f(c[m][t][0] + b2v[t]);
            const float v1 = sigmoid_f(c[m][t][1] + b2v[t]);
            const float v2 = sigmoid_f(c[m][t][2] + b2v[t]);
            const float v3 = sigmoid_f(c[m][t][3] + b2v[t]);
            const uint2 pk = make_uint2(bf16pk(v0, v1), bf16pk(v2, v3));
            *reinterpret_cast<uint2*>(wl + 1280 + (c16 + 16 * t) * 36 + 8 * m + 2 * hq) = pk;
        }
    }

    // ---- read V B-frags + run ids ----
    bf16x8 vb[2][2];
    unsigned rid[2][8];
#pragma unroll
    for (int kk = 0; kk < 2; ++kk) {
#pragma unroll
        for (int t = 0; t < 2; ++t) {
            const uint4 vv = *reinterpret_cast<const uint4*>(wl + 1280 + (c16 + 16 * t) * 36 + 16 * kk + 4 * hq);
            vb[kk][t] = __builtin_bit_cast(bf16x8, vv);
        }
        const uint4 r0 = *reinterpret_cast<const uint4*>(wl + 2432 + 32 * kk + 8 * hq);
        const uint4 r1 = *reinterpret_cast<const uint4*>(wl + 2432 + 32 * kk + 8 * hq + 4);
        rid[kk][0] = r0.x; rid[kk][1] = r0.y; rid[kk][2] = r0.z; rid[kk][3] = r0.w;
        rid[kk][4] = r1.x; rid[kk][5] = r1.y; rid[kk][6] = r1.z; rid[kk][7] = r1.w;
    }

    // ---- MFMA2: agg_runs = I x V, then predicated atomics ----
    const int nm = (nruns + 15) >> 4;
    for (int mr = 0; mr < nm; ++mr) {
        const unsigned rowg = (unsigned)(16 * mr + c16);
        f32x4 d0 = {0.f, 0.f, 0.f, 0.f};
        f32x4 d1 = {0.f, 0.f, 0.f, 0.f};
#pragma unroll
        for (int kk = 0; kk < 2; ++kk) {
            unsigned iw[4];
#pragma unroll
            for (int w = 0; w < 4; ++w) {
                iw[w] = (rid[kk][2 * w]     == rowg ? 0x3f80u : 0u)
                      | (rid[kk][2 * w + 1] == rowg ? 0x3f800000u : 0u);
            }
            const bf16x8 ifr = __builtin_bit_cast(bf16x8, make_uint4(iw[0], iw[1], iw[2], iw[3]));
            d0 = __builtin_amdgcn_mfma_f32_16x16x32_bf16(ifr, vb[kk][0], d0, 0, 0, 0);
            d1 = __builtin_amdgcn_mfma_f32_16x16x32_bf16(ifr, vb[kk][1], d1, 0, 0, 0);
        }
#pragma unroll
        for (int r = 0; r < 4; ++r) {
            const int rn = 16 * mr + 4 * hq + r;
            const unsigned tr = wl[2496 + (rn & 63)];
            if (rn < nruns) {
                float* dst = agg + ((size_t)b * Nn + tr) * 32;
                atomicAdd(dst + c16,      d0[r]);
                atomicAdd(dst + c16 + 16, d1[r]);
            }
        }
    }
}

__global__ __launch_bounds__(256) void node_kernel(
    const float* __restrict__ W3, const float* __restrict__ b3,
    float* __restrict__ out)
{
    const int idx = blockIdx.x * 256 + threadIdx.x;
    if (idx >= Bc * Nn) return;
    float* row = out + (size_t)idx * OD;

    float a[EO];
#pragma unroll
    for (int i = 0; i < EO / 4; ++i) {
        float4 t = reinterpret_cast<float4*>(row)[i];
        a[4 * i] = t.x; a[4 * i + 1] = t.y; a[4 * i + 2] = t.z; a[4 * i + 3] = t.w;
    }
    float r[OD];
#pragma unroll
    for (int p = 0; p < OD; ++p) {
        const float* wr = W3 + p * EO;
        float s = b3[p];
#pragma unroll
        for (int o = 0; o < EO; ++o) s += a[o] * wr[o];
        r[p] = sigmoid_f(s);
    }
#pragma unroll
    for (int i = 0; i < OD / 4; ++i) {
        float4 t;
        t.x = r[4 * i + 0]; t.y = r[4 * i + 1];
        t.z = r[4 * i + 2]; t.w = r[4 * i + 3];
        reinterpret_cast<float4*>(row)[i] = t;
    }
}

extern "C" void kernel_launch(void* const* d_in, const int* in_sizes, int n_in,
                              void* d_out, int out_size, void* d_ws, size_t ws_size,
                              hipStream_t stream) {
    const float* x     = (const float*)d_in[0];
    const float* ea    = (const float*)d_in[1];
    const float* wmean = (const float*)d_in[2];
    const float* wstd  = (const float*)d_in[3];
    const float* W1    = (const float*)d_in[4];
    const float* b1    = (const float*)d_in[5];
    const float* W2    = (const float*)d_in[6];
    const float* b2    = (const float*)d_in[7];
    const float* W3    = (const float*)d_in[8];
    const float* b3    = (const float*)d_in[9];
    const int*   ei    = (const int*)d_in[10];
    float* out = (float*)d_out;
    float* ws  = (float*)d_ws;

    // d_out doubles as the agg accumulator; zero it + stats/histogram region.
    hipMemsetAsync(d_out, 0, (size_t)out_size * sizeof(float), stream);
    hipMemsetAsync(d_ws, 0, (U_CNT + Nn) * sizeof(float), stream);

    stats_hist_kernel<<<256, 256, 0, stream>>>(ea, ei, ws);
    scan_kernel<<<1, 256, 0, stream>>>(ws);
    record_kernel<<<Ec / 256, 256, 0, stream>>>(ei, ea, ws);
    precompute_kernel<<<(Bc * Nn + 255) / 256, 256, 0, stream>>>(x, wmean, wstd, W1, b1, ws);
    edge_kernel<<<(Ec / 256) * Bc, 256, 0, stream>>>(W1, W2, b2, ws, out);
    node_kernel<<<(Bc * Nn + 255) / 256, 256, 0, stream>>>(W3, b3, out);
}

// Round 6
// 204.727 us; speedup vs baseline: 20.8980x; 1.1427x over previous
//
#include <hip/hip_runtime.h>
#include <hip/hip_fp16.h>
#include <cmath>

constexpr int Bc = 8;
constexpr int Nn = 10000;
constexpr int Ec = 320000;
constexpr int IN = 16;
constexpr int EH = 32;
constexpr int EO = 32;
constexpr int OD = 32;

// ws layout (u32 offsets):
//   [0..3] s0,s1,q0,q1 (zeroed, float)   [4..7] mean0,mean1,istd0,istd1 (float)
constexpr size_t U_CNT = 8;                             // Nn ints (zeroed)
constexpr size_t U_CUR = U_CNT + Nn;                    // Nn ints
constexpr size_t U_REC = 20016;                         // 4*Ec u32, 16B-aligned
constexpr size_t U_PA  = U_REC + 4 * (size_t)Ec;        // Bc*Nn*16 u32 (fp16x32 rows)
constexpr size_t U_PB  = U_PA + (size_t)Bc * Nn * 16;
constexpr size_t U_PW  = U_PB + (size_t)Bc * Nn * 16;   // 2*Bc*Nn u32 (float2)
// end = U_PW + 2*Bc*Nn = 4,020,016 u32 = 16.1 MB

constexpr int HIST_BLOCKS = 256;
constexpr int PRE_BLOCKS  = (Bc * Nn + 255) / 256;      // 313
constexpr int ZERO_BLOCKS = 512;

typedef short bf16x8 __attribute__((ext_vector_type(8)));
typedef float f32x4 __attribute__((ext_vector_type(4)));

__device__ __forceinline__ float sigmoid_f(float x) {
    return __builtin_amdgcn_rcpf(1.0f + __expf(-x));
}
__device__ __forceinline__ unsigned bf16r(float f) {
    unsigned u = __builtin_bit_cast(unsigned, f);
    return (u + 0x7FFFu + ((u >> 16) & 1u)) >> 16;
}
__device__ __forceinline__ unsigned bf16pk(float lo, float hi) {
    return bf16r(lo) | (bf16r(hi) << 16);
}

// Fused: [0,256) stats+hist | [256,569) precompute PA/PB/PW | [569,1081) zero d_out
__global__ __launch_bounds__(256) void prep_kernel(
    const float* __restrict__ ea, const int* __restrict__ ei,
    const float* __restrict__ x, const float* __restrict__ wmean,
    const float* __restrict__ wstd, const float* __restrict__ W1,
    const float* __restrict__ b1, float* __restrict__ ws,
    float* __restrict__ out)
{
    const int blk = blockIdx.x;
    const int tid = threadIdx.x;

    if (blk < HIST_BLOCKS) {
        // ---- stats + histogram over edges [blk*1250, blk*1250+1250) ----
        int* cnt = (int*)ws + U_CNT;
        const int lo = blk * (Ec / HIST_BLOCKS);
        const int hi = lo + (Ec / HIST_BLOCKS);
        float s0 = 0.f, s1 = 0.f, q0 = 0.f, q1 = 0.f;
        for (int i = lo + tid; i < hi; i += 256) {
            float2 v = reinterpret_cast<const float2*>(ea)[i];
            s0 += v.x; s1 += v.y; q0 += v.x * v.x; q1 += v.y * v.y;
            atomicAdd(&cnt[ei[Ec + i]], 1);
        }
#pragma unroll
        for (int off = 32; off > 0; off >>= 1) {
            s0 += __shfl_down(s0, off);
            s1 += __shfl_down(s1, off);
            q0 += __shfl_down(q0, off);
            q1 += __shfl_down(q1, off);
        }
        if ((tid & 63) == 0) {
            atomicAdd(&ws[0], s0);
            atomicAdd(&ws[1], s1);
            atomicAdd(&ws[2], q0);
            atomicAdd(&ws[3], q1);
        }
    } else if (blk < HIST_BLOCKS + PRE_BLOCKS) {
        // ---- precompute PA/PB (fp16) + PW per (b,n) ----
        const int idx = (blk - HIST_BLOCKS) * 256 + tid;
        if (idx >= Bc * Nn) return;
        const float4* xr = reinterpret_cast<const float4*>(x + (size_t)idx * IN);
        float xv[16];
        float4 t;
        t = xr[0]; xv[0]  = t.x; xv[1]  = t.y; xv[2]  = t.z; xv[3]  = t.w;
        t = xr[1]; xv[4]  = t.x; xv[5]  = t.y; xv[6]  = t.z; xv[7]  = t.w;
        t = xr[2]; xv[8]  = t.x; xv[9]  = t.y; xv[10] = t.z; xv[11] = t.w;
        t = xr[3]; xv[12] = t.x; xv[13] = t.y; xv[14] = t.z; xv[15] = t.w;

        __half2* PA = reinterpret_cast<__half2*>((unsigned*)ws + U_PA) + (size_t)idx * 16;
        __half2* PB = reinterpret_cast<__half2*>((unsigned*)ws + U_PB) + (size_t)idx * 16;
#pragma unroll
        for (int p = 0; p < 16; ++p) {
            float a[2], bb[2];
#pragma unroll
            for (int j = 0; j < 2; ++j) {
                const int o = 2 * p + j;
                const float* wr = W1 + o * 35;
                float av = 0.f, bv = b1[o];
#pragma unroll
                for (int f = 0; f < 16; ++f) {
                    av += xv[f] * wr[f];
                    bv += xv[f] * wr[16 + f];
                }
                a[j] = av; bb[j] = bv;
            }
            PA[p] = __half2{__float2half(a[0]), __float2half(a[1])};
            PB[p] = __half2{__float2half(bb[0]), __float2half(bb[1])};
        }
        float2* PW = reinterpret_cast<float2*>((unsigned*)ws + U_PW);
        PW[idx] = make_float2(3.0f * (xv[14] * wstd[0] + wmean[0]),
                              xv[15] * wstd[1] + wmean[1]);
    } else {
        // ---- zero d_out (agg accumulator) ----
        float4* o4 = reinterpret_cast<float4*>(out);
        constexpr int TOT4 = Bc * Nn * 32 / 4;           // 640000
        const float4 z = make_float4(0.f, 0.f, 0.f, 0.f);
        for (int i = (blk - HIST_BLOCKS - PRE_BLOCKS) * 256 + tid; i < TOT4;
             i += ZERO_BLOCKS * 256)
            o4[i] = z;
    }
}

// One block, 1024 threads: finalize stats + exclusive scan cnt -> cursor.
__global__ __launch_bounds__(1024) void scan_kernel(float* __restrict__ ws) {
    const int tid = threadIdx.x;
    const int lane = tid & 63;
    const int w = tid >> 6;                              // 16 waves
    if (tid == 0) {
        float s0 = ws[0], s1 = ws[1], q0 = ws[2], q1 = ws[3];
        float m0 = s0 / (float)Ec, m1 = s1 / (float)Ec;
        float v0 = (q0 - s0 * m0) / (float)(Ec - 1);
        float v1 = (q1 - s1 * m1) / (float)(Ec - 1);
        ws[4] = m0; ws[5] = m1;
        ws[6] = rsqrtf(v0); ws[7] = rsqrtf(v1);
    }
    int* cnt    = (int*)ws + U_CNT;
    int* cursor = (int*)ws + U_CUR;

    constexpr int PER = 10;                              // 1024*10 >= Nn
    const int lo = tid * PER;
    int local[PER];
    int sum = 0;
#pragma unroll
    for (int k = 0; k < PER; ++k) {
        const int i = lo + k;
        const int c = (i < Nn) ? cnt[i] : 0;
        local[k] = sum;                                  // exclusive within-thread
        sum += c;
    }
    // inclusive wave scan of per-thread sums
    int v = sum;
#pragma unroll
    for (int off = 1; off < 64; off <<= 1) {
        int u = __shfl_up(v, off);
        if (lane >= off) v += u;
    }
    __shared__ int wt[16];
    __shared__ int woff[16];
    if (lane == 63) wt[w] = v;
    __syncthreads();
    if (w == 0) {                                        // wave 0 scans the 16 totals
        int t = (lane < 16) ? wt[lane] : 0;
        int tv = t;
#pragma unroll
        for (int off = 1; off < 16; off <<= 1) {
            int u = __shfl_up(tv, off);
            if (lane >= off) tv += u;
        }
        if (lane < 16) woff[lane] = tv - t;              // exclusive
    }
    __syncthreads();
    const int base = woff[w] + (v - sum);                // block-exclusive prefix for this thread
#pragma unroll
    for (int k = 0; k < PER; ++k) {
        const int i = lo + k;
        if (i < Nn) cursor[i] = base + local[k];
    }
}

// Build sorted 16B edge records {src, tgt, ea.x, ea.y}.
__global__ __launch_bounds__(256) void record_kernel(const int* __restrict__ ei,
                                                     const float* __restrict__ ea,
                                                     float* __restrict__ ws) {
    int* cursor = (int*)ws + U_CUR;
    uint4* rec  = reinterpret_cast<uint4*>((unsigned*)ws + U_REC);
    const int e = blockIdx.x * 256 + threadIdx.x;
    const int src = ei[e];
    const int tgt = ei[Ec + e];
    const float2 v = reinterpret_cast<const float2*>(ea)[e];
    const int pos = atomicAdd(&cursor[tgt], 1);
    rec[pos] = make_uint4((unsigned)src, (unsigned)tgt,
                          __builtin_bit_cast(unsigned, v.x),
                          __builtin_bit_cast(unsigned, v.y));
}

// LDS layout per wave (u32 words): [0..1280) h-tile 64 rows x 20 (32 bf16 + pad)
//   [1280..2432) V-tile 32 rows x 36   [2432..2496) runid   [2496..2560) runtgt
__global__ __launch_bounds__(256, 4) void edge_kernel(
    const float* __restrict__ W1, const float* __restrict__ W2,
    const float* __restrict__ b2, const float* __restrict__ ws,
    float* __restrict__ agg)
{
    __shared__ unsigned lds[4 * 2560];
    const int tid  = threadIdx.x;
    const int lane = tid & 63;
    const int wid  = tid >> 6;
    unsigned* wl = lds + wid * 2560;

    const int bid = blockIdx.x;
    const int b   = bid & 7;                       // XCD-resident batch
    const int gid = (bid >> 3) * 256 + wid * 64 + lane;

    const unsigned* wsu = (const unsigned*)ws;
    const uint4 rec = reinterpret_cast<const uint4*>(wsu + U_REC)[gid];
    const int src = (int)rec.x;
    const int tgt = (int)rec.y;
    const float eax = __builtin_bit_cast(float, rec.z);
    const float eay = __builtin_bit_cast(float, rec.w);

    // ---- phase 1: gather + layer-1 finish + sigmoid -> h (packed bf16) ----
    const float2 pw = reinterpret_cast<const float2*>(wsu + U_PW)[b * Nn + src];
    const float theta = fabsf(eay - pw.y);
    const float ewt = fmaxf(pw.x * __cosf(theta * 22.5f) * __builtin_amdgcn_rcpf(eax), 0.0f);
    const float f32v = (eax - ws[4]) * ws[6];
    const float f33v = (eay - ws[5]) * ws[7];

    const uint4* pa4 = reinterpret_cast<const uint4*>(wsu + U_PA + ((size_t)b * Nn + src) * 16);
    const uint4* pb4 = reinterpret_cast<const uint4*>(wsu + U_PB + ((size_t)b * Nn + tgt) * 16);

    unsigned hw[16];
#pragma unroll
    for (int q = 0; q < 4; ++q) {
        const uint4 ua = pa4[q];
        const uint4 ub = pb4[q];
        const unsigned au[4] = {ua.x, ua.y, ua.z, ua.w};
        const unsigned bu[4] = {ub.x, ub.y, ub.z, ub.w};
#pragma unroll
        for (int j = 0; j < 4; ++j) {
            const int p = 4 * q + j;            // half2 index: outputs 2p, 2p+1
            const __half2 s = __hadd2(__builtin_bit_cast(__half2, au[j]),
                                      __builtin_bit_cast(__half2, bu[j]));
            const float2 f = __half22float2(s);
            const int o0 = 2 * p, o1 = 2 * p + 1;
            const float acc0 = f.x + f32v * W1[o0 * 35 + 32]
                                   + f33v * W1[o0 * 35 + 33]
                                   + ewt  * W1[o0 * 35 + 34];
            const float acc1 = f.y + f32v * W1[o1 * 35 + 32]
                                   + f33v * W1[o1 * 35 + 33]
                                   + ewt  * W1[o1 * 35 + 34];
            hw[p] = bf16pk(sigmoid_f(acc0), sigmoid_f(acc1));
        }
    }
    {
        uint4* hrow = reinterpret_cast<uint4*>(wl + lane * 20);
#pragma unroll
        for (int q = 0; q < 4; ++q)
            hrow[q] = make_uint4(hw[4*q], hw[4*q+1], hw[4*q+2], hw[4*q+3]);
    }

    // ---- run ids (edges sorted by tgt) ----
    const int tprev = __shfl_up(tgt, 1);
    const bool head = (lane == 0) || (tprev != tgt);
    const unsigned long long mask = __ballot(head);
    const unsigned long long mle = (~0ULL) >> (63 - lane);
    const int run = __popcll(mask & mle) - 1;
    const int nruns = __popcll(mask);
    wl[2432 + lane] = (unsigned)run;
    if (head) wl[2496 + run] = (unsigned)tgt;

    const int c16 = lane & 15;
    const int hq  = lane >> 4;

    // ---- W2 B-frags: lane holds out=(c16+16t), k=8*hq+j ----
    bf16x8 bw[2];
#pragma unroll
    for (int t = 0; t < 2; ++t) {
        const float* wr = W2 + (c16 + 16 * t) * 32 + 8 * hq;
        const float4 w0 = *reinterpret_cast<const float4*>(wr);
        const float4 w1 = *reinterpret_cast<const float4*>(wr + 4);
        const uint4 pk = make_uint4(bf16pk(w0.x, w0.y), bf16pk(w0.z, w0.w),
                                    bf16pk(w1.x, w1.y), bf16pk(w1.z, w1.w));
        bw[t] = __builtin_bit_cast(bf16x8, pk);
    }

    // ---- MFMA1: C[edge][out] = H x W2^T ----
    f32x4 c[4][2];
#pragma unroll
    for (int m = 0; m < 4; ++m) {
        const uint4 av = *reinterpret_cast<const uint4*>(wl + (16 * m + c16) * 20 + 4 * hq);
        const bf16x8 afr = __builtin_bit_cast(bf16x8, av);
#pragma unroll
        for (int t = 0; t < 2; ++t) {
            f32x4 z = {0.f, 0.f, 0.f, 0.f};
            c[m][t] = __builtin_amdgcn_mfma_f32_16x16x32_bf16(afr, bw[t], z, 0, 0, 0);
        }
    }

    // ---- bias + sigmoid + pack V -> LDS [out][edge] bf16 ----
    const float b2v[2] = { b2[c16], b2[c16 + 16] };
#pragma unroll
    for (int m = 0; m < 4; ++m) {
#pragma unroll
        for (int t = 0; t < 2; ++t) {
            const float v0 = sigmoid_f(c[m][t][0] + b2v[t]);
            const float v1 = sigmoid_f(c[m][t][1] + b2v[t]);
            const float v2 = sigmoid_f(c[m][t][2] + b2v[t]);
            const float v3 = sigmoid_f(c[m][t][3] + b2v[t]);
            const uint2 pk = make_uint2(bf16pk(v0, v1), bf16pk(v2, v3));
            *reinterpret_cast<uint2*>(wl + 1280 + (c16 + 16 * t) * 36 + 8 * m + 2 * hq) = pk;
        }
    }

    // ---- read V B-frags + run ids ----
    bf16x8 vb[2][2];
    unsigned rid[2][8];
#pragma unroll
    for (int kk = 0; kk < 2; ++kk) {
#pragma unroll
        for (int t = 0; t < 2; ++t) {
            const uint4 vv = *reinterpret_cast<const uint4*>(wl + 1280 + (c16 + 16 * t) * 36 + 16 * kk + 4 * hq);
            vb[kk][t] = __builtin_bit_cast(bf16x8, vv);
        }
        const uint4 r0 = *reinterpret_cast<const uint4*>(wl + 2432 + 32 * kk + 8 * hq);
        const uint4 r1 = *reinterpret_cast<const uint4*>(wl + 2432 + 32 * kk + 8 * hq + 4);
        rid[kk][0] = r0.x; rid[kk][1] = r0.y; rid[kk][2] = r0.z; rid[kk][3] = r0.w;
        rid[kk][4] = r1.x; rid[kk][5] = r1.y; rid[kk][6] = r1.z; rid[kk][7] = r1.w;
    }

    // ---- MFMA2: agg_runs = I x V, then predicated atomics ----
    const int nm = (nruns + 15) >> 4;
    for (int mr = 0; mr < nm; ++mr) {
        const unsigned rowg = (unsigned)(16 * mr + c16);
        f32x4 d0 = {0.f, 0.f, 0.f, 0.f};
        f32x4 d1 = {0.f, 0.f, 0.f, 0.f};
#pragma unroll
        for (int kk = 0; kk < 2; ++kk) {
            unsigned iw[4];
#pragma unroll
            for (int w = 0; w < 4; ++w) {
                iw[w] = (rid[kk][2 * w]     == rowg ? 0x3f80u : 0u)
                      | (rid[kk][2 * w + 1] == rowg ? 0x3f800000u : 0u);
            }
            const bf16x8 ifr = __builtin_bit_cast(bf16x8, make_uint4(iw[0], iw[1], iw[2], iw[3]));
            d0 = __builtin_amdgcn_mfma_f32_16x16x32_bf16(ifr, vb[kk][0], d0, 0, 0, 0);
            d1 = __builtin_amdgcn_mfma_f32_16x16x32_bf16(ifr, vb[kk][1], d1, 0, 0, 0);
        }
#pragma unroll
        for (int r = 0; r < 4; ++r) {
            const int rn = 16 * mr + 4 * hq + r;
            const unsigned tr = wl[2496 + (rn & 63)];
            if (rn < nruns) {
                float* dst = agg + ((size_t)b * Nn + tr) * 32;
                atomicAdd(dst + c16,      d0[r]);
                atomicAdd(dst + c16 + 16, d1[r]);
            }
        }
    }
}

__global__ __launch_bounds__(256) void node_kernel(
    const float* __restrict__ W3, const float* __restrict__ b3,
    float* __restrict__ out)
{
    const int idx = blockIdx.x * 256 + threadIdx.x;
    if (idx >= Bc * Nn) return;
    float* row = out + (size_t)idx * OD;

    float a[EO];
#pragma unroll
    for (int i = 0; i < EO / 4; ++i) {
        float4 t = reinterpret_cast<float4*>(row)[i];
        a[4 * i] = t.x; a[4 * i + 1] = t.y; a[4 * i + 2] = t.z; a[4 * i + 3] = t.w;
    }
    float r[OD];
#pragma unroll
    for (int p = 0; p < OD; ++p) {
        const float* wr = W3 + p * EO;
        float s = b3[p];
#pragma unroll
        for (int o = 0; o < EO; ++o) s += a[o] * wr[o];
        r[p] = sigmoid_f(s);
    }
#pragma unroll
    for (int i = 0; i < OD / 4; ++i) {
        float4 t;
        t.x = r[4 * i + 0]; t.y = r[4 * i + 1];
        t.z = r[4 * i + 2]; t.w = r[4 * i + 3];
        reinterpret_cast<float4*>(row)[i] = t;
    }
}

extern "C" void kernel_launch(void* const* d_in, const int* in_sizes, int n_in,
                              void* d_out, int out_size, void* d_ws, size_t ws_size,
                              hipStream_t stream) {
    const float* x     = (const float*)d_in[0];
    const float* ea    = (const float*)d_in[1];
    const float* wmean = (const float*)d_in[2];
    const float* wstd  = (const float*)d_in[3];
    const float* W1    = (const float*)d_in[4];
    const float* b1    = (const float*)d_in[5];
    const float* W2    = (const float*)d_in[6];
    const float* b2    = (const float*)d_in[7];
    const float* W3    = (const float*)d_in[8];
    const float* b3    = (const float*)d_in[9];
    const int*   ei    = (const int*)d_in[10];
    float* out = (float*)d_out;
    float* ws  = (float*)d_ws;

    // Zero stats sums + histogram (cursor/records/PA/PB/PW are fully overwritten).
    hipMemsetAsync(d_ws, 0, (U_CNT + Nn) * sizeof(float), stream);

    prep_kernel<<<HIST_BLOCKS + PRE_BLOCKS + ZERO_BLOCKS, 256, 0, stream>>>(
        ea, ei, x, wmean, wstd, W1, b1, ws, out);
    scan_kernel<<<1, 1024, 0, stream>>>(ws);
    record_kernel<<<Ec / 256, 256, 0, stream>>>(ei, ea, ws);
    edge_kernel<<<(Ec / 256) * Bc, 256, 0, stream>>>(W1, W2, b2, ws, out);
    node_kernel<<<(Bc * Nn + 255) / 256, 256, 0, stream>>>(W3, b3, out);
}

// Round 8
// 198.911 us; speedup vs baseline: 21.5090x; 1.0292x over previous
//
#include <hip/hip_runtime.h>
#include <hip/hip_fp16.h>
#include <cmath>

constexpr int Bc = 8;
constexpr int Nn = 10000;
constexpr int Ec = 320000;
constexpr int IN = 16;
constexpr int EH = 32;
constexpr int EO = 32;
constexpr int OD = 32;

// ws layout (u32 offsets):
//   [0..3] s0,s1,q0,q1 (zeroed, float)   [4..7] mean0,mean1,istd0,istd1
constexpr size_t U_CNT = 8;                             // Nn ints (zeroed)
constexpr size_t U_CUR = U_CNT + Nn;                    // Nn ints
constexpr size_t U_REC = 20016;                         // 4*Ec u32, 16B-aligned
constexpr size_t U_PA  = U_REC + 4 * (size_t)Ec;        // Bc*Nn*16 u32 (fp16x32 rows)
constexpr size_t U_PB  = U_PA + (size_t)Bc * Nn * 16;
constexpr size_t U_PW  = U_PB + (size_t)Bc * Nn * 16;   // 2*Bc*Nn u32 (float2)

constexpr int HIST_BLOCKS = 256;
constexpr int PRE_BLOCKS  = (Bc * Nn + 255) / 256;      // 313
constexpr int ZERO_BLOCKS = 512;

// per-wave LDS (u32 words): h-tile [0,1280) 64r x 20; V-tile [0,1152) 32r x 36 (OVERLAY,
// written only after MFMA1 drains); runid [1280,1344); runtgt [1344,1408)
constexpr int WPW = 1408;

typedef short bf16x8 __attribute__((ext_vector_type(8)));
typedef float f32x4 __attribute__((ext_vector_type(4)));

__device__ __forceinline__ float sigmoid_f(float x) {
    return __builtin_amdgcn_rcpf(1.0f + __expf(-x));
}
__device__ __forceinline__ unsigned bf16r(float f) {
    unsigned u = __builtin_bit_cast(unsigned, f);
    return (u + 0x7FFFu + ((u >> 16) & 1u)) >> 16;
}
__device__ __forceinline__ unsigned bf16pk(float lo, float hi) {
    return bf16r(lo) | (bf16r(hi) << 16);
}

// Fused: [0,256) stats+hist | [256,569) precompute PA/PB/PW | [569,1081) zero d_out
__global__ __launch_bounds__(256) void prep_kernel(
    const float* __restrict__ ea, const int* __restrict__ ei,
    const float* __restrict__ x, const float* __restrict__ wmean,
    const float* __restrict__ wstd, const float* __restrict__ W1,
    const float* __restrict__ b1, float* __restrict__ ws,
    float* __restrict__ out)
{
    const int blk = blockIdx.x;
    const int tid = threadIdx.x;

    if (blk < HIST_BLOCKS) {
        int* cnt = (int*)ws + U_CNT;
        const int lo = blk * (Ec / HIST_BLOCKS);
        const int hi = lo + (Ec / HIST_BLOCKS);
        float s0 = 0.f, s1 = 0.f, q0 = 0.f, q1 = 0.f;
        for (int i = lo + tid; i < hi; i += 256) {
            float2 v = reinterpret_cast<const float2*>(ea)[i];
            s0 += v.x; s1 += v.y; q0 += v.x * v.x; q1 += v.y * v.y;
            atomicAdd(&cnt[ei[Ec + i]], 1);
        }
#pragma unroll
        for (int off = 32; off > 0; off >>= 1) {
            s0 += __shfl_down(s0, off);
            s1 += __shfl_down(s1, off);
            q0 += __shfl_down(q0, off);
            q1 += __shfl_down(q1, off);
        }
        if ((tid & 63) == 0) {
            atomicAdd(&ws[0], s0);
            atomicAdd(&ws[1], s1);
            atomicAdd(&ws[2], q0);
            atomicAdd(&ws[3], q1);
        }
    } else if (blk < HIST_BLOCKS + PRE_BLOCKS) {
        const int idx = (blk - HIST_BLOCKS) * 256 + tid;
        if (idx >= Bc * Nn) return;
        const float4* xr = reinterpret_cast<const float4*>(x + (size_t)idx * IN);
        float xv[16];
        float4 t;
        t = xr[0]; xv[0]  = t.x; xv[1]  = t.y; xv[2]  = t.z; xv[3]  = t.w;
        t = xr[1]; xv[4]  = t.x; xv[5]  = t.y; xv[6]  = t.z; xv[7]  = t.w;
        t = xr[2]; xv[8]  = t.x; xv[9]  = t.y; xv[10] = t.z; xv[11] = t.w;
        t = xr[3]; xv[12] = t.x; xv[13] = t.y; xv[14] = t.z; xv[15] = t.w;

        __half2* PA = reinterpret_cast<__half2*>((unsigned*)ws + U_PA) + (size_t)idx * 16;
        __half2* PB = reinterpret_cast<__half2*>((unsigned*)ws + U_PB) + (size_t)idx * 16;
#pragma unroll
        for (int p = 0; p < 16; ++p) {
            float a[2], bb[2];
#pragma unroll
            for (int j = 0; j < 2; ++j) {
                const int o = 2 * p + j;
                const float* wr = W1 + o * 35;
                float av = 0.f, bv = b1[o];
#pragma unroll
                for (int f = 0; f < 16; ++f) {
                    av += xv[f] * wr[f];
                    bv += xv[f] * wr[16 + f];
                }
                a[j] = av; bb[j] = bv;
            }
            PA[p] = __half2{__float2half(a[0]), __float2half(a[1])};
            PB[p] = __half2{__float2half(bb[0]), __float2half(bb[1])};
        }
        float2* PW = reinterpret_cast<float2*>((unsigned*)ws + U_PW);
        PW[idx] = make_float2(3.0f * (xv[14] * wstd[0] + wmean[0]),
                              xv[15] * wstd[1] + wmean[1]);
    } else {
        float4* o4 = reinterpret_cast<float4*>(out);
        constexpr int TOT4 = Bc * Nn * 32 / 4;
        const float4 z = make_float4(0.f, 0.f, 0.f, 0.f);
        for (int i = (blk - HIST_BLOCKS - PRE_BLOCKS) * 256 + tid; i < TOT4;
             i += ZERO_BLOCKS * 256)
            o4[i] = z;
    }
}

// One block, 1024 threads: finalize stats + exclusive scan cnt -> cursor.
__global__ __launch_bounds__(1024) void scan_kernel(float* __restrict__ ws) {
    const int tid = threadIdx.x;
    const int lane = tid & 63;
    const int w = tid >> 6;
    if (tid == 0) {
        float s0 = ws[0], s1 = ws[1], q0 = ws[2], q1 = ws[3];
        float m0 = s0 / (float)Ec, m1 = s1 / (float)Ec;
        float v0 = (q0 - s0 * m0) / (float)(Ec - 1);
        float v1 = (q1 - s1 * m1) / (float)(Ec - 1);
        ws[4] = m0; ws[5] = m1;
        ws[6] = rsqrtf(v0); ws[7] = rsqrtf(v1);
    }
    int* cnt    = (int*)ws + U_CNT;
    int* cursor = (int*)ws + U_CUR;

    constexpr int PER = 10;
    const int lo = tid * PER;
    int local[PER];
    int sum = 0;
#pragma unroll
    for (int k = 0; k < PER; ++k) {
        const int i = lo + k;
        const int c = (i < Nn) ? cnt[i] : 0;
        local[k] = sum;
        sum += c;
    }
    int v = sum;
#pragma unroll
    for (int off = 1; off < 64; off <<= 1) {
        int u = __shfl_up(v, off);
        if (lane >= off) v += u;
    }
    __shared__ int wt[16];
    __shared__ int woff[16];
    if (lane == 63) wt[w] = v;
    __syncthreads();
    if (w == 0) {
        int t = (lane < 16) ? wt[lane] : 0;
        int tv = t;
#pragma unroll
        for (int off = 1; off < 16; off <<= 1) {
            int u = __shfl_up(tv, off);
            if (lane >= off) tv += u;
        }
        if (lane < 16) woff[lane] = tv - t;
    }
    __syncthreads();
    const int base = woff[w] + (v - sum);
#pragma unroll
    for (int k = 0; k < PER; ++k) {
        const int i = lo + k;
        if (i < Nn) cursor[i] = base + local[k];
    }
}

// Build sorted 16B edge records {src, tgt, ea.x, ea.y}.
__global__ __launch_bounds__(256) void record_kernel(const int* __restrict__ ei,
                                                     const float* __restrict__ ea,
                                                     float* __restrict__ ws) {
    int* cursor = (int*)ws + U_CUR;
    uint4* rec  = reinterpret_cast<uint4*>((unsigned*)ws + U_REC);
    const int e = blockIdx.x * 256 + threadIdx.x;
    const int src = ei[e];
    const int tgt = ei[Ec + e];
    const float2 v = reinterpret_cast<const float2*>(ea)[e];
    const int pos = atomicAdd(&cursor[tgt], 1);
    rec[pos] = make_uint4((unsigned)src, (unsigned)tgt,
                          __builtin_bit_cast(unsigned, v.x),
                          __builtin_bit_cast(unsigned, v.y));
}

__global__ __launch_bounds__(256, 7) void edge_kernel(
    const float* __restrict__ W1, const float* __restrict__ W2,
    const float* __restrict__ b2, const float* __restrict__ ws,
    float* __restrict__ agg)
{
    __shared__ unsigned lds[4 * WPW];
    const int tid  = threadIdx.x;
    const int lane = tid & 63;
    const int wid  = tid >> 6;
    unsigned* wl = lds + wid * WPW;

    const int bid = blockIdx.x;
    const int b   = bid & 7;                       // XCD-resident batch
    const int gid = (bid >> 3) * 256 + wid * 64 + lane;

    const unsigned* wsu = (const unsigned*)ws;
    const uint4 rec = reinterpret_cast<const uint4*>(wsu + U_REC)[gid];
    const int src = (int)rec.x;
    const int tgt = (int)rec.y;
    const float eax = __builtin_bit_cast(float, rec.z);
    const float eay = __builtin_bit_cast(float, rec.w);

    // ---- phase 1: gather + layer-1 finish + sigmoid -> h (packed bf16) ----
    const float2 pw = reinterpret_cast<const float2*>(wsu + U_PW)[b * Nn + src];
    const float theta = fabsf(eay - pw.y);
    const float ewt = fmaxf(pw.x * __cosf(theta * 22.5f) * __builtin_amdgcn_rcpf(eax), 0.0f);
    const float f32v = (eax - ws[4]) * ws[6];
    const float f33v = (eay - ws[5]) * ws[7];

    const uint4* pa4 = reinterpret_cast<const uint4*>(wsu + U_PA + ((size_t)b * Nn + src) * 16);
    const uint4* pb4 = reinterpret_cast<const uint4*>(wsu + U_PB + ((size_t)b * Nn + tgt) * 16);

    unsigned hw[16];
#pragma unroll
    for (int q = 0; q < 4; ++q) {
        const uint4 ua = pa4[q];
        const uint4 ub = pb4[q];
        const unsigned au[4] = {ua.x, ua.y, ua.z, ua.w};
        const unsigned bu[4] = {ub.x, ub.y, ub.z, ub.w};
#pragma unroll
        for (int j = 0; j < 4; ++j) {
            const int p = 4 * q + j;            // half2 index: outputs 2p, 2p+1
            const __half2 s = __hadd2(__builtin_bit_cast(__half2, au[j]),
                                      __builtin_bit_cast(__half2, bu[j]));
            const float2 f = __half22float2(s);
            const int o0 = 2 * p, o1 = 2 * p + 1;
            const float acc0 = f.x + f32v * W1[o0 * 35 + 32]
                                   + f33v * W1[o0 * 35 + 33]
                                   + ewt  * W1[o0 * 35 + 34];
            const float acc1 = f.y + f32v * W1[o1 * 35 + 32]
                                   + f33v * W1[o1 * 35 + 33]
                                   + ewt  * W1[o1 * 35 + 34];
            hw[p] = bf16pk(sigmoid_f(acc0), sigmoid_f(acc1));
        }
    }
    {
        uint4* hrow = reinterpret_cast<uint4*>(wl + lane * 20);
#pragma unroll
        for (int q = 0; q < 4; ++q)
            hrow[q] = make_uint4(hw[4*q], hw[4*q+1], hw[4*q+2], hw[4*q+3]);
    }

    // ---- run ids (edges sorted by tgt) ----
    const int tprev = __shfl_up(tgt, 1);
    const bool head = (lane == 0) || (tprev != tgt);
    const unsigned long long mask = __ballot(head);
    const unsigned long long mle = (~0ULL) >> (63 - lane);
    const int run = __popcll(mask & mle) - 1;
    const int nruns = __popcll(mask);
    wl[1280 + lane] = (unsigned)run;
    if (head) wl[1344 + run] = (unsigned)tgt;

    const int c16 = lane & 15;
    const int hq  = lane >> 4;

    // ---- W2 B-frags: lane holds out=(c16+16t), k=8*hq+j ----
    bf16x8 bw[2];
#pragma unroll
    for (int t = 0; t < 2; ++t) {
        const float* wr = W2 + (c16 + 16 * t) * 32 + 8 * hq;
        const float4 w0 = *reinterpret_cast<const float4*>(wr);
        const float4 w1 = *reinterpret_cast<const float4*>(wr + 4);
        const uint4 pk = make_uint4(bf16pk(w0.x, w0.y), bf16pk(w0.z, w0.w),
                                    bf16pk(w1.x, w1.y), bf16pk(w1.z, w1.w));
        bw[t] = __builtin_bit_cast(bf16x8, pk);
    }

    // ---- MFMA1: C[edge][out] = H x W2^T ----
    f32x4 c[4][2];
#pragma unroll
    for (int m = 0; m < 4; ++m) {
        const uint4 av = *reinterpret_cast<const uint4*>(wl + (16 * m + c16) * 20 + 4 * hq);
        const bf16x8 afr = __builtin_bit_cast(bf16x8, av);
#pragma unroll
        for (int t = 0; t < 2; ++t) {
            f32x4 z = {0.f, 0.f, 0.f, 0.f};
            c[m][t] = __builtin_amdgcn_mfma_f32_16x16x32_bf16(afr, bw[t], z, 0, 0, 0);
        }
    }

    // Drain all outstanding LDS reads before overlaying the h region with V.
    __builtin_amdgcn_sched_barrier(0);
    asm volatile("s_waitcnt lgkmcnt(0)" ::: "memory");
    __builtin_amdgcn_sched_barrier(0);

    // ---- bias + sigmoid + pack V -> LDS [out][edge] bf16 (overlay at 0) ----
    const float b2v[2] = { b2[c16], b2[c16 + 16] };
#pragma unroll
    for (int m = 0; m < 4; ++m) {
#pragma unroll
        for (int t = 0; t < 2; ++t) {
            const float v0 = sigmoid_f(c[m][t][0] + b2v[t]);
            const float v1 = sigmoid_f(c[m][t][1] + b2v[t]);
            const float v2 = sigmoid_f(c[m][t][2] + b2v[t]);
            const float v3 = sigmoid_f(c[m][t][3] + b2v[t]);
            const uint2 pk = make_uint2(bf16pk(v0, v1), bf16pk(v2, v3));
            *reinterpret_cast<uint2*>(wl + (c16 + 16 * t) * 36 + 8 * m + 2 * hq) = pk;
        }
    }

    // ---- read V B-frags + run ids ----
    bf16x8 vb[2][2];
    unsigned rid[2][8];
#pragma unroll
    for (int kk = 0; kk < 2; ++kk) {
#pragma unroll
        for (int t = 0; t < 2; ++t) {
            const uint4 vv = *reinterpret_cast<const uint4*>(wl + (c16 + 16 * t) * 36 + 16 * kk + 4 * hq);
            vb[kk][t] = __builtin_bit_cast(bf16x8, vv);
        }
        const uint4 r0 = *reinterpret_cast<const uint4*>(wl + 1280 + 32 * kk + 8 * hq);
        const uint4 r1 = *reinterpret_cast<const uint4*>(wl + 1280 + 32 * kk + 8 * hq + 4);
        rid[kk][0] = r0.x; rid[kk][1] = r0.y; rid[kk][2] = r0.z; rid[kk][3] = r0.w;
        rid[kk][4] = r1.x; rid[kk][5] = r1.y; rid[kk][6] = r1.z; rid[kk][7] = r1.w;
    }

    // ---- MFMA2: agg_runs = I x V, then predicated atomics ----
    const int nm = (nruns + 15) >> 4;
    for (int mr = 0; mr < nm; ++mr) {
        const unsigned rowg = (unsigned)(16 * mr + c16);
        f32x4 d0 = {0.f, 0.f, 0.f, 0.f};
        f32x4 d1 = {0.f, 0.f, 0.f, 0.f};
#pragma unroll
        for (int kk = 0; kk < 2; ++kk) {
            unsigned iw[4];
#pragma unroll
            for (int w = 0; w < 4; ++w) {
                iw[w] = (rid[kk][2 * w]     == rowg ? 0x3f80u : 0u)
                      | (rid[kk][2 * w + 1] == rowg ? 0x3f800000u : 0u);
            }
            const bf16x8 ifr = __builtin_bit_cast(bf16x8, make_uint4(iw[0], iw[1], iw[2], iw[3]));
            d0 = __builtin_amdgcn_mfma_f32_16x16x32_bf16(ifr, vb[kk][0], d0, 0, 0, 0);
            d1 = __builtin_amdgcn_mfma_f32_16x16x32_bf16(ifr, vb[kk][1], d1, 0, 0, 0);
        }
#pragma unroll
        for (int r = 0; r < 4; ++r) {
            const int rn = 16 * mr + 4 * hq + r;
            const unsigned tr = wl[1344 + (rn & 63)];
            if (rn < nruns) {
                float* dst = agg + ((size_t)b * Nn + tr) * 32;
                atomicAdd(dst + c16,      d0[r]);
                atomicAdd(dst + c16 + 16, d1[r]);
            }
        }
    }
}

__global__ __launch_bounds__(256) void node_kernel(
    const float* __restrict__ W3, const float* __restrict__ b3,
    float* __restrict__ out)
{
    const int idx = blockIdx.x * 256 + threadIdx.x;
    if (idx >= Bc * Nn) return;
    float* row = out + (size_t)idx * OD;

    float a[EO];
#pragma unroll
    for (int i = 0; i < EO / 4; ++i) {
        float4 t = reinterpret_cast<float4*>(row)[i];
        a[4 * i] = t.x; a[4 * i + 1] = t.y; a[4 * i + 2] = t.z; a[4 * i + 3] = t.w;
    }
    float r[OD];
#pragma unroll
    for (int p = 0; p < OD; ++p) {
        const float* wr = W3 + p * EO;
        float s = b3[p];
#pragma unroll
        for (int o = 0; o < EO; ++o) s += a[o] * wr[o];
        r[p] = sigmoid_f(s);
    }
#pragma unroll
    for (int i = 0; i < OD / 4; ++i) {
        float4 t;
        t.x = r[4 * i + 0]; t.y = r[4 * i + 1];
        t.z = r[4 * i + 2]; t.w = r[4 * i + 3];
        reinterpret_cast<float4*>(row)[i] = t;
    }
}

extern "C" void kernel_launch(void* const* d_in, const int* in_sizes, int n_in,
                              void* d_out, int out_size, void* d_ws, size_t ws_size,
                              hipStream_t stream) {
    const float* x     = (const float*)d_in[0];
    const float* ea    = (const float*)d_in[1];
    const float* wmean = (const float*)d_in[2];
    const float* wstd  = (const float*)d_in[3];
    const float* W1    = (const float*)d_in[4];
    const float* b1    = (const float*)d_in[5];
    const float* W2    = (const float*)d_in[6];
    const float* b2    = (const float*)d_in[7];
    const float* W3    = (const float*)d_in[8];
    const float* b3    = (const float*)d_in[9];
    const int*   ei    = (const int*)d_in[10];
    float* out = (float*)d_out;
    float* ws  = (float*)d_ws;

    hipMemsetAsync(d_ws, 0, (U_CNT + Nn) * sizeof(float), stream);

    prep_kernel<<<HIST_BLOCKS + PRE_BLOCKS + ZERO_BLOCKS, 256, 0, stream>>>(
        ea, ei, x, wmean, wstd, W1, b1, ws, out);
    scan_kernel<<<1, 1024, 0, stream>>>(ws);
    record_kernel<<<Ec / 256, 256, 0, stream>>>(ei, ea, ws);
    edge_kernel<<<(Ec / 256) * Bc, 256, 0, stream>>>(W1, W2, b2, ws, out);
    node_kernel<<<(Bc * Nn + 255) / 256, 256, 0, stream>>>(W3, b3, out);
}

// Round 10
// 195.530 us; speedup vs baseline: 21.8809x; 1.0173x over previous
//
#include <hip/hip_runtime.h>
#include <hip/hip_fp16.h>
#include <cmath>

constexpr int Bc = 8;
constexpr int Nn = 10000;
constexpr int Ec = 320000;
constexpr int IN = 16;
constexpr int EH = 32;
constexpr int EO = 32;
constexpr int OD = 32;

// ws layout (u32 offsets):
//   [0..3] s0,s1,q0,q1 (zeroed, float)   [4..7] mean0,mean1,istd0,istd1
constexpr size_t U_CNT = 8;                             // Nn ints (zeroed)
constexpr size_t U_CUR = U_CNT + Nn;                    // Nn ints
constexpr size_t U_REC = 20016;                         // 4*Ec u32, 16B-aligned
constexpr size_t U_PA  = U_REC + 4 * (size_t)Ec;        // Bc*Nn*16 u32 (fp16x32 rows)
constexpr size_t U_PB  = U_PA + (size_t)Bc * Nn * 16;
constexpr size_t U_PW  = U_PB + (size_t)Bc * Nn * 16;   // 2*Bc*Nn u32 (float2)

constexpr int HIST_BLOCKS = 256;
constexpr int PRE_BLOCKS  = (Bc * Nn + 255) / 256;      // 313
constexpr int ZERO_BLOCKS = 512;

// per-wave LDS (u32 words): h-tile [0,1280) 64r x 20; V-tile [0,1152) 32r x 36 (OVERLAY,
// written only after MFMA1 drains); runid [1280,1344); runtgt [1344,1408)
constexpr int WPW = 1408;

typedef _Float16 f16x8 __attribute__((ext_vector_type(8)));
typedef float f32x4 __attribute__((ext_vector_type(4)));

__device__ __forceinline__ float sigmoid_f(float x) {
    return __builtin_amdgcn_rcpf(1.0f + __expf(-x));
}
// Single-instruction f32x2 -> f16x2 pack (v_cvt_pkrtz_f16_f32, standard builtin).
__device__ __forceinline__ unsigned pkh(float lo, float hi) {
    return __builtin_bit_cast(unsigned, __builtin_amdgcn_cvt_pkrtz(lo, hi));
}

// Fused: [0,256) stats+hist | [256,569) precompute PA/PB/PW | [569,1081) zero d_out
__global__ __launch_bounds__(256) void prep_kernel(
    const float* __restrict__ ea, const int* __restrict__ ei,
    const float* __restrict__ x, const float* __restrict__ wmean,
    const float* __restrict__ wstd, const float* __restrict__ W1,
    const float* __restrict__ b1, float* __restrict__ ws,
    float* __restrict__ out)
{
    const int blk = blockIdx.x;
    const int tid = threadIdx.x;

    if (blk < HIST_BLOCKS) {
        int* cnt = (int*)ws + U_CNT;
        const int lo = blk * (Ec / HIST_BLOCKS);
        const int hi = lo + (Ec / HIST_BLOCKS);
        float s0 = 0.f, s1 = 0.f, q0 = 0.f, q1 = 0.f;
        for (int i = lo + tid; i < hi; i += 256) {
            float2 v = reinterpret_cast<const float2*>(ea)[i];
            s0 += v.x; s1 += v.y; q0 += v.x * v.x; q1 += v.y * v.y;
            atomicAdd(&cnt[ei[Ec + i]], 1);
        }
#pragma unroll
        for (int off = 32; off > 0; off >>= 1) {
            s0 += __shfl_down(s0, off);
            s1 += __shfl_down(s1, off);
            q0 += __shfl_down(q0, off);
            q1 += __shfl_down(q1, off);
        }
        if ((tid & 63) == 0) {
            atomicAdd(&ws[0], s0);
            atomicAdd(&ws[1], s1);
            atomicAdd(&ws[2], q0);
            atomicAdd(&ws[3], q1);
        }
    } else if (blk < HIST_BLOCKS + PRE_BLOCKS) {
        const int idx = (blk - HIST_BLOCKS) * 256 + tid;
        if (idx >= Bc * Nn) return;
        const float4* xr = reinterpret_cast<const float4*>(x + (size_t)idx * IN);
        float xv[16];
        float4 t;
        t = xr[0]; xv[0]  = t.x; xv[1]  = t.y; xv[2]  = t.z; xv[3]  = t.w;
        t = xr[1]; xv[4]  = t.x; xv[5]  = t.y; xv[6]  = t.z; xv[7]  = t.w;
        t = xr[2]; xv[8]  = t.x; xv[9]  = t.y; xv[10] = t.z; xv[11] = t.w;
        t = xr[3]; xv[12] = t.x; xv[13] = t.y; xv[14] = t.z; xv[15] = t.w;

        __half2* PA = reinterpret_cast<__half2*>((unsigned*)ws + U_PA) + (size_t)idx * 16;
        __half2* PB = reinterpret_cast<__half2*>((unsigned*)ws + U_PB) + (size_t)idx * 16;
#pragma unroll
        for (int p = 0; p < 16; ++p) {
            float a[2], bb[2];
#pragma unroll
            for (int j = 0; j < 2; ++j) {
                const int o = 2 * p + j;
                const float* wr = W1 + o * 35;
                float av = 0.f, bv = b1[o];
#pragma unroll
                for (int f = 0; f < 16; ++f) {
                    av += xv[f] * wr[f];
                    bv += xv[f] * wr[16 + f];
                }
                a[j] = av; bb[j] = bv;
            }
            PA[p] = __half2{__float2half(a[0]), __float2half(a[1])};
            PB[p] = __half2{__float2half(bb[0]), __float2half(bb[1])};
        }
        float2* PW = reinterpret_cast<float2*>((unsigned*)ws + U_PW);
        PW[idx] = make_float2(3.0f * (xv[14] * wstd[0] + wmean[0]),
                              xv[15] * wstd[1] + wmean[1]);
    } else {
        float4* o4 = reinterpret_cast<float4*>(out);
        constexpr int TOT4 = Bc * Nn * 32 / 4;
        const float4 z = make_float4(0.f, 0.f, 0.f, 0.f);
        for (int i = (blk - HIST_BLOCKS - PRE_BLOCKS) * 256 + tid; i < TOT4;
             i += ZERO_BLOCKS * 256)
            o4[i] = z;
    }
}

// One block, 1024 threads: finalize stats + exclusive scan cnt -> cursor.
__global__ __launch_bounds__(1024) void scan_kernel(float* __restrict__ ws) {
    const int tid = threadIdx.x;
    const int lane = tid & 63;
    const int w = tid >> 6;
    if (tid == 0) {
        float s0 = ws[0], s1 = ws[1], q0 = ws[2], q1 = ws[3];
        float m0 = s0 / (float)Ec, m1 = s1 / (float)Ec;
        float v0 = (q0 - s0 * m0) / (float)(Ec - 1);
        float v1 = (q1 - s1 * m1) / (float)(Ec - 1);
        ws[4] = m0; ws[5] = m1;
        ws[6] = rsqrtf(v0); ws[7] = rsqrtf(v1);
    }
    int* cnt    = (int*)ws + U_CNT;
    int* cursor = (int*)ws + U_CUR;

    constexpr int PER = 10;
    const int lo = tid * PER;
    int local[PER];
    int sum = 0;
#pragma unroll
    for (int k = 0; k < PER; ++k) {
        const int i = lo + k;
        const int c = (i < Nn) ? cnt[i] : 0;
        local[k] = sum;
        sum += c;
    }
    int v = sum;
#pragma unroll
    for (int off = 1; off < 64; off <<= 1) {
        int u = __shfl_up(v, off);
        if (lane >= off) v += u;
    }
    __shared__ int wt[16];
    __shared__ int woff[16];
    if (lane == 63) wt[w] = v;
    __syncthreads();
    if (w == 0) {
        int t = (lane < 16) ? wt[lane] : 0;
        int tv = t;
#pragma unroll
        for (int off = 1; off < 16; off <<= 1) {
            int u = __shfl_up(tv, off);
            if (lane >= off) tv += u;
        }
        if (lane < 16) woff[lane] = tv - t;
    }
    __syncthreads();
    const int base = woff[w] + (v - sum);
#pragma unroll
    for (int k = 0; k < PER; ++k) {
        const int i = lo + k;
        if (i < Nn) cursor[i] = base + local[k];
    }
}

// Build sorted 16B edge records {src, tgt, ea.x, ea.y}.
__global__ __launch_bounds__(256) void record_kernel(const int* __restrict__ ei,
                                                     const float* __restrict__ ea,
                                                     float* __restrict__ ws) {
    int* cursor = (int*)ws + U_CUR;
    uint4* rec  = reinterpret_cast<uint4*>((unsigned*)ws + U_REC);
    const int e = blockIdx.x * 256 + threadIdx.x;
    const int src = ei[e];
    const int tgt = ei[Ec + e];
    const float2 v = reinterpret_cast<const float2*>(ea)[e];
    const int pos = atomicAdd(&cursor[tgt], 1);
    rec[pos] = make_uint4((unsigned)src, (unsigned)tgt,
                          __builtin_bit_cast(unsigned, v.x),
                          __builtin_bit_cast(unsigned, v.y));
}

__global__ __launch_bounds__(256, 7) void edge_kernel(
    const float* __restrict__ W1, const float* __restrict__ W2,
    const float* __restrict__ b2, const float* __restrict__ ws,
    float* __restrict__ agg)
{
    __shared__ unsigned lds[4 * WPW];
    const int tid  = threadIdx.x;
    const int lane = tid & 63;
    const int wid  = tid >> 6;
    unsigned* wl = lds + wid * WPW;

    const int bid = blockIdx.x;
    const int b   = bid & 7;                       // XCD-resident batch
    const int gid = (bid >> 3) * 256 + wid * 64 + lane;

    const unsigned* wsu = (const unsigned*)ws;
    const uint4 rec = reinterpret_cast<const uint4*>(wsu + U_REC)[gid];
    const int src = (int)rec.x;
    const int tgt = (int)rec.y;
    const float eax = __builtin_bit_cast(float, rec.z);
    const float eay = __builtin_bit_cast(float, rec.w);

    // ---- phase 1: gather + layer-1 finish + sigmoid -> h (packed fp16) ----
    const float2 pw = reinterpret_cast<const float2*>(wsu + U_PW)[b * Nn + src];
    const float theta = fabsf(eay - pw.y);
    const float ewt = fmaxf(pw.x * __cosf(theta * 22.5f) * __builtin_amdgcn_rcpf(eax), 0.0f);
    const float f32v = (eax - ws[4]) * ws[6];
    const float f33v = (eay - ws[5]) * ws[7];

    const uint4* pa4 = reinterpret_cast<const uint4*>(wsu + U_PA + ((size_t)b * Nn + src) * 16);
    const uint4* pb4 = reinterpret_cast<const uint4*>(wsu + U_PB + ((size_t)b * Nn + tgt) * 16);

    unsigned hw[16];
#pragma unroll
    for (int q = 0; q < 4; ++q) {
        const uint4 ua = pa4[q];
        const uint4 ub = pb4[q];
        const unsigned au[4] = {ua.x, ua.y, ua.z, ua.w};
        const unsigned bu[4] = {ub.x, ub.y, ub.z, ub.w};
#pragma unroll
        for (int j = 0; j < 4; ++j) {
            const int p = 4 * q + j;            // half2 index: outputs 2p, 2p+1
            const __half2 s = __hadd2(__builtin_bit_cast(__half2, au[j]),
                                      __builtin_bit_cast(__half2, bu[j]));
            const float2 f = __half22float2(s);
            const int o0 = 2 * p, o1 = 2 * p + 1;
            const float acc0 = f.x + f32v * W1[o0 * 35 + 32]
                                   + f33v * W1[o0 * 35 + 33]
                                   + ewt  * W1[o0 * 35 + 34];
            const float acc1 = f.y + f32v * W1[o1 * 35 + 32]
                                   + f33v * W1[o1 * 35 + 33]
                                   + ewt  * W1[o1 * 35 + 34];
            hw[p] = pkh(sigmoid_f(acc0), sigmoid_f(acc1));
        }
    }
    {
        uint4* hrow = reinterpret_cast<uint4*>(wl + lane * 20);
#pragma unroll
        for (int q = 0; q < 4; ++q)
            hrow[q] = make_uint4(hw[4*q], hw[4*q+1], hw[4*q+2], hw[4*q+3]);
    }

    // ---- run ids (edges sorted by tgt) ----
    const int tprev = __shfl_up(tgt, 1);
    const bool head = (lane == 0) || (tprev != tgt);
    const unsigned long long mask = __ballot(head);
    const unsigned long long mle = (~0ULL) >> (63 - lane);
    const int run = __popcll(mask & mle) - 1;
    const int nruns = __popcll(mask);
    wl[1280 + lane] = (unsigned)run;
    if (head) wl[1344 + run] = (unsigned)tgt;

    const int c16 = lane & 15;
    const int hq  = lane >> 4;

    // ---- W2 B-frags (fp16): lane holds out=(c16+16t), k=8*hq+j ----
    f16x8 bw[2];
#pragma unroll
    for (int t = 0; t < 2; ++t) {
        const float* wr = W2 + (c16 + 16 * t) * 32 + 8 * hq;
        const float4 w0 = *reinterpret_cast<const float4*>(wr);
        const float4 w1 = *reinterpret_cast<const float4*>(wr + 4);
        const uint4 pk = make_uint4(pkh(w0.x, w0.y), pkh(w0.z, w0.w),
                                    pkh(w1.x, w1.y), pkh(w1.z, w1.w));
        bw[t] = __builtin_bit_cast(f16x8, pk);
    }

    // ---- MFMA1 (f16): C[edge][out] = H x W2^T ----
    f32x4 c[4][2];
#pragma unroll
    for (int m = 0; m < 4; ++m) {
        const uint4 av = *reinterpret_cast<const uint4*>(wl + (16 * m + c16) * 20 + 4 * hq);
        const f16x8 afr = __builtin_bit_cast(f16x8, av);
#pragma unroll
        for (int t = 0; t < 2; ++t) {
            f32x4 z = {0.f, 0.f, 0.f, 0.f};
            c[m][t] = __builtin_amdgcn_mfma_f32_16x16x32_f16(afr, bw[t], z, 0, 0, 0);
        }
    }

    // Drain all outstanding LDS reads before overlaying the h region with V.
    __builtin_amdgcn_sched_barrier(0);
    asm volatile("s_waitcnt lgkmcnt(0)" ::: "memory");
    __builtin_amdgcn_sched_barrier(0);

    // ---- bias + sigmoid + pack V -> LDS [out][edge] fp16 (overlay at 0) ----
    const float b2v[2] = { b2[c16], b2[c16 + 16] };
#pragma unroll
    for (int m = 0; m < 4; ++m) {
#pragma unroll
        for (int t = 0; t < 2; ++t) {
            const float v0 = sigmoid_f(c[m][t][0] + b2v[t]);
            const float v1 = sigmoid_f(c[m][t][1] + b2v[t]);
            const float v2 = sigmoid_f(c[m][t][2] + b2v[t]);
            const float v3 = sigmoid_f(c[m][t][3] + b2v[t]);
            const uint2 pk = make_uint2(pkh(v0, v1), pkh(v2, v3));
            *reinterpret_cast<uint2*>(wl + (c16 + 16 * t) * 36 + 8 * m + 2 * hq) = pk;
        }
    }

    // ---- read V B-frags + run ids ----
    f16x8 vb[2][2];
    unsigned rid[2][8];
#pragma unroll
    for (int kk = 0; kk < 2; ++kk) {
#pragma unroll
        for (int t = 0; t < 2; ++t) {
            const uint4 vv = *reinterpret_cast<const uint4*>(wl + (c16 + 16 * t) * 36 + 16 * kk + 4 * hq);
            vb[kk][t] = __builtin_bit_cast(f16x8, vv);
        }
        const uint4 r0 = *reinterpret_cast<const uint4*>(wl + 1280 + 32 * kk + 8 * hq);
        const uint4 r1 = *reinterpret_cast<const uint4*>(wl + 1280 + 32 * kk + 8 * hq + 4);
        rid[kk][0] = r0.x; rid[kk][1] = r0.y; rid[kk][2] = r0.z; rid[kk][3] = r0.w;
        rid[kk][4] = r1.x; rid[kk][5] = r1.y; rid[kk][6] = r1.z; rid[kk][7] = r1.w;
    }

    // ---- MFMA2 (f16): agg_runs = I x V, then predicated atomics ----
    const int nm = (nruns + 15) >> 4;
    for (int mr = 0; mr < nm; ++mr) {
        const unsigned rowg = (unsigned)(16 * mr + c16);
        f32x4 d0 = {0.f, 0.f, 0.f, 0.f};
        f32x4 d1 = {0.f, 0.f, 0.f, 0.f};
#pragma unroll
        for (int kk = 0; kk < 2; ++kk) {
            unsigned iw[4];
#pragma unroll
            for (int w = 0; w < 4; ++w) {
                iw[w] = (rid[kk][2 * w]     == rowg ? 0x3C00u : 0u)        // fp16 1.0
                      | (rid[kk][2 * w + 1] == rowg ? 0x3C000000u : 0u);
            }
            const f16x8 ifr = __builtin_bit_cast(f16x8, make_uint4(iw[0], iw[1], iw[2], iw[3]));
            d0 = __builtin_amdgcn_mfma_f32_16x16x32_f16(ifr, vb[kk][0], d0, 0, 0, 0);
            d1 = __builtin_amdgcn_mfma_f32_16x16x32_f16(ifr, vb[kk][1], d1, 0, 0, 0);
        }
#pragma unroll
        for (int r = 0; r < 4; ++r) {
            const int rn = 16 * mr + 4 * hq + r;
            const unsigned tr = wl[1344 + (rn & 63)];
            if (rn < nruns) {
                float* dst = agg + ((size_t)b * Nn + tr) * 32;
                atomicAdd(dst + c16,      d0[r]);
                atomicAdd(dst + c16 + 16, d1[r]);
            }
        }
    }
}

__global__ __launch_bounds__(256) void node_kernel(
    const float* __restrict__ W3, const float* __restrict__ b3,
    float* __restrict__ out)
{
    const int idx = blockIdx.x * 256 + threadIdx.x;
    if (idx >= Bc * Nn) return;
    float* row = out + (size_t)idx * OD;

    float a[EO];
#pragma unroll
    for (int i = 0; i < EO / 4; ++i) {
        float4 t = reinterpret_cast<float4*>(row)[i];
        a[4 * i] = t.x; a[4 * i + 1] = t.y; a[4 * i + 2] = t.z; a[4 * i + 3] = t.w;
    }
    float r[OD];
#pragma unroll
    for (int p = 0; p < OD; ++p) {
        const float* wr = W3 + p * EO;
        float s = b3[p];
#pragma unroll
        for (int o = 0; o < EO; ++o) s += a[o] * wr[o];
        r[p] = sigmoid_f(s);
    }
#pragma unroll
    for (int i = 0; i < OD / 4; ++i) {
        float4 t;
        t.x = r[4 * i + 0]; t.y = r[4 * i + 1];
        t.z = r[4 * i + 2]; t.w = r[4 * i + 3];
        reinterpret_cast<float4*>(row)[i] = t;
    }
}

extern "C" void kernel_launch(void* const* d_in, const int* in_sizes, int n_in,
                              void* d_out, int out_size, void* d_ws, size_t ws_size,
                              hipStream_t stream) {
    const float* x     = (const float*)d_in[0];
    const float* ea    = (const float*)d_in[1];
    const float* wmean = (const float*)d_in[2];
    const float* wstd  = (const float*)d_in[3];
    const float* W1    = (const float*)d_in[4];
    const float* b1    = (const float*)d_in[5];
    const float* W2    = (const float*)d_in[6];
    const float* b2    = (const float*)d_in[7];
    const float* W3    = (const float*)d_in[8];
    const float* b3    = (const float*)d_in[9];
    const int*   ei    = (const int*)d_in[10];
    float* out = (float*)d_out;
    float* ws  = (float*)d_ws;

    hipMemsetAsync(d_ws, 0, (U_CNT + Nn) * sizeof(float), stream);

    prep_kernel<<<HIST_BLOCKS + PRE_BLOCKS + ZERO_BLOCKS, 256, 0, stream>>>(
        ea, ei, x, wmean, wstd, W1, b1, ws, out);
    scan_kernel<<<1, 1024, 0, stream>>>(ws);
    record_kernel<<<Ec / 256, 256, 0, stream>>>(ei, ea, ws);
    edge_kernel<<<(Ec / 256) * Bc, 256, 0, stream>>>(W1, W2, b2, ws, out);
    node_kernel<<<(Bc * Nn + 255) / 256, 256, 0, stream>>>(W3, b3, out);
}